// Round 2
// baseline (2663.845 us; speedup 1.0000x reference)
//
#include <hip/hip_runtime.h>
#include <hip/hip_bf16.h>
#include <math.h>

#define HID 64
#define NBASES 8
#define NNODES 16
#define NDIM 4
#define BATCH 2048
#define NPAIRS 120
#define XCOLS 921

// column offsets in output X
#define COL_Z 0
#define COL_D 64
#define COL_INVD 184
#define COL_INVSQ 304
#define COL_EXPD 424
#define COL_SCR 544
#define COL_LOGD 664
#define COL_PW 784
#define COL_ND 904
#define COL_GL 920

__device__ __forceinline__ float fast_rcp(float x) {
    return __builtin_amdgcn_rcpf(x);
}

__device__ __forceinline__ float silu_f(float x) {
    // x * sigmoid(x) = x / (1 + exp(-x))
    return x * fast_rcp(1.0f + __expf(-x));
}

__device__ __forceinline__ float to_out(float v) {
    return fminf(fmaxf(v, -1000000.0f), 1000000.0f);
}

// ---------------- sel gate: s[b] = sigmoid(MLP(z[b])) ----------------
__global__ __launch_bounds__(64) void sel_kernel(
    const float* __restrict__ z,
    const float* __restrict__ W1, const float* __restrict__ b1,   // (64,64),(64)
    const float* __restrict__ W2, const float* __restrict__ b2,   // (64,32),(32)
    const float* __restrict__ W3, const float* __restrict__ b3,   // (32,1),(1)
    float* __restrict__ s_out)
{
    int b = blockIdx.x;
    int t = threadIdx.x;
    __shared__ float zs[64];
    __shared__ float h1[64];
    __shared__ float h2[32];
    zs[t] = z[b * 64 + t];
    __syncthreads();
    {
        float acc = b1[t];
        #pragma unroll
        for (int i = 0; i < 64; ++i) acc += zs[i] * W1[i * 64 + t];
        h1[t] = silu_f(acc);
    }
    __syncthreads();
    if (t < 32) {
        float acc = b2[t];
        #pragma unroll
        for (int i = 0; i < 64; ++i) acc += h1[i] * W2[i * 32 + t];
        h2[t] = silu_f(acc);
    }
    __syncthreads();
    if (t == 0) {
        float acc = b3[0];
        #pragma unroll
        for (int i = 0; i < 32; ++i) acc += h2[i] * W3[i];
        s_out[b] = fast_rcp(1.0f + __expf(-acc));
    }
}

// ---------------- geometry features + gated z columns ----------------
__global__ __launch_bounds__(128) void geom_kernel(
    const float* __restrict__ z, const float* __restrict__ s_gate,
    float* __restrict__ out)
{
    int b = blockIdx.x;
    int t = threadIdx.x;
    __shared__ float zs[64];
    if (t < 64) zs[t] = z[b * 64 + t];
    __syncthreads();
    float s = s_gate[b];
    float* row = out + (size_t)b * XCOLS;
    if (t < 64) row[COL_Z + t] = to_out(zs[t] * s);
    if (t < NPAIRS) {
        int p = t;
        int i = 0, pp = p;
        while (pp >= 15 - i) { pp -= 15 - i; ++i; }
        int j = i + 1 + pp;
        float dx = zs[i * 4 + 0] - zs[j * 4 + 0];
        float dy = zs[i * 4 + 1] - zs[j * 4 + 1];
        float d = sqrtf(dx * dx + dy * dy);
        d = fmaxf(d, 0.001f);
        float inv_d = fast_rcp(d + 0.1f);
        float inv_sq = fast_rcp(d * d + 0.1f);
        float exp_d = __expf(-fminf(d, 20.0f));
        float screened = exp_d * inv_d;
        float log_d = __logf(d + 1.0f);
        row[COL_D + p] = to_out(d * s);
        row[COL_INVD + p] = to_out(inv_d * s);
        row[COL_INVSQ + p] = to_out(inv_sq * s);
        row[COL_EXPD + p] = to_out(exp_d * s);
        row[COL_SCR + p] = to_out(screened * s);
        row[COL_LOGD + p] = to_out(log_d * s);
    }
}

// ---------------- basis MLP: one thread per row ----------------
// MODE 0 = pw (din=8, pair gather), 1 = nd (din=4, node), 2 = gl (din=64)
template <int DIN, int MODE>
__global__ __launch_bounds__(256) void basis_kernel(
    const float* __restrict__ z,
    const float* __restrict__ W1, const float* __restrict__ b1,
    const float* __restrict__ W2, const float* __restrict__ b2,
    const float* __restrict__ W3, const float* __restrict__ b3,
    const float* __restrict__ scale,
    const float* __restrict__ aW1, const float* __restrict__ ab1,
    const float* __restrict__ aW2, const float* __restrict__ ab2,
    const float* __restrict__ res,
    const float* __restrict__ s_gate,
    float* __restrict__ out, int nrows)
{
    int r = blockIdx.x * blockDim.x + threadIdx.x;
    if (r >= nrows) return;

    int b, col;
    float x[DIN];
    if (MODE == 0) {
        b = r / NPAIRS;
        int p = r - b * NPAIRS;
        int i = 0, pp = p;
        while (pp >= 15 - i) { pp -= 15 - i; ++i; }
        int j = i + 1 + pp;
        const float* zb = z + b * 64;
        #pragma unroll
        for (int q = 0; q < 4; ++q) x[q] = zb[i * 4 + q];
        #pragma unroll
        for (int q = 0; q < 4; ++q) x[4 + q] = zb[j * 4 + q];
        col = COL_PW + p;
    } else if (MODE == 1) {
        b = r / NNODES;
        int node = r - b * NNODES;
        const float* zb = z + b * 64;
        #pragma unroll
        for (int q = 0; q < 4; ++q) x[q] = zb[node * 4 + q];
        col = COL_ND + node;
    } else {
        b = r;
        const float* zb = z + b * 64;
        #pragma unroll
        for (int q = 0; q < 64; ++q) x[q] = zb[q];
        col = COL_GL;
    }

    // ---- attention branch ----
    float att[NBASES];
    {
        float a1[HID / 2];
        #pragma unroll
        for (int jj = 0; jj < HID / 2; ++jj) {
            float acc = ab1[jj];
            #pragma unroll
            for (int ii = 0; ii < DIN; ++ii) acc += x[ii] * aW1[ii * (HID / 2) + jj];
            a1[jj] = silu_f(acc);
        }
        #pragma unroll
        for (int n = 0; n < NBASES; ++n) {
            float acc = ab2[n];
            #pragma unroll
            for (int jj = 0; jj < HID / 2; ++jj) acc += a1[jj] * aW2[jj * NBASES + n];
            att[n] = acc;
        }
        float m = att[0];
        #pragma unroll
        for (int n = 1; n < NBASES; ++n) m = fmaxf(m, att[n]);
        float sum = 0.0f;
        #pragma unroll
        for (int n = 0; n < NBASES; ++n) { att[n] = __expf(att[n] - m); sum += att[n]; }
        float inv = fast_rcp(sum);
        #pragma unroll
        for (int n = 0; n < NBASES; ++n) att[n] *= inv;
    }

    // ---- 8 bases ----
    float outv = 0.0f;
    for (int n = 0; n < NBASES; ++n) {
        const float* W1n = W1 + n * DIN * HID;
        const float* b1n = b1 + n * HID;
        const float* W2n = W2 + n * HID * HID;
        const float* b2n = b2 + n * HID;
        const float* W3n = W3 + n * HID;  // W3 is (NB, HID, 1)

        float h1[HID];
        #pragma unroll
        for (int h = 0; h < HID; ++h) {
            float acc = b1n[h];
            #pragma unroll
            for (int ii = 0; ii < DIN; ++ii) acc += x[ii] * W1n[ii * HID + h];
            h1[h] = silu_f(acc);
        }

        float h2[HID];
        #pragma unroll
        for (int k = 0; k < HID; ++k) h2[k] = b2n[k];
        for (int h = 0; h < HID; ++h) {
            float hv = h1[h];
            const float* wrow = W2n + h * HID;
            #pragma unroll
            for (int k = 0; k < HID; ++k) h2[k] += hv * wrow[k];
        }

        float acc = b3[n];  // b3 is (NB,1)
        #pragma unroll
        for (int k = 0; k < HID; ++k) acc += silu_f(h2[k]) * W3n[k];
        outv += att[n] * acc * scale[n];
    }

    float mean = 0.0f;
    #pragma unroll
    for (int ii = 0; ii < DIN; ++ii) mean += x[ii];
    mean *= (1.0f / (float)DIN);
    outv += res[0] * mean;

    out[(size_t)b * XCOLS + col] = to_out(outv * s_gate[b]);
}

extern "C" void kernel_launch(void* const* d_in, const int* in_sizes, int n_in,
                              void* d_out, int out_size, void* d_ws, size_t ws_size,
                              hipStream_t stream) {
    const float* z = (const float*)d_in[0];
    // pw params at 1..12, nd at 13..24, gl at 25..36 (order: W1,b1,W2,b2,W3,b3,scale,aW1,ab1,aW2,ab2,res)
    const float* pw[12]; const float* nd[12]; const float* gl[12];
    for (int i = 0; i < 12; ++i) pw[i] = (const float*)d_in[1 + i];
    for (int i = 0; i < 12; ++i) nd[i] = (const float*)d_in[13 + i];
    for (int i = 0; i < 12; ++i) gl[i] = (const float*)d_in[25 + i];
    const float* sel_W1 = (const float*)d_in[37];
    const float* sel_b1 = (const float*)d_in[38];
    const float* sel_W2 = (const float*)d_in[39];
    const float* sel_b2 = (const float*)d_in[40];
    const float* sel_W3 = (const float*)d_in[41];
    const float* sel_b3 = (const float*)d_in[42];

    float* out = (float*)d_out;
    float* s_ws = (float*)d_ws;  // BATCH floats

    sel_kernel<<<BATCH, 64, 0, stream>>>(z, sel_W1, sel_b1, sel_W2, sel_b2, sel_W3, sel_b3, s_ws);
    geom_kernel<<<BATCH, 128, 0, stream>>>(z, s_ws, out);

    int nrows_pw = BATCH * NPAIRS;
    basis_kernel<8, 0><<<(nrows_pw + 255) / 256, 256, 0, stream>>>(
        z, pw[0], pw[1], pw[2], pw[3], pw[4], pw[5], pw[6], pw[7], pw[8], pw[9], pw[10], pw[11],
        s_ws, out, nrows_pw);

    int nrows_nd = BATCH * NNODES;
    basis_kernel<4, 1><<<(nrows_nd + 255) / 256, 256, 0, stream>>>(
        z, nd[0], nd[1], nd[2], nd[3], nd[4], nd[5], nd[6], nd[7], nd[8], nd[9], nd[10], nd[11],
        s_ws, out, nrows_nd);

    int nrows_gl = BATCH;
    basis_kernel<64, 2><<<(nrows_gl + 255) / 256, 256, 0, stream>>>(
        z, gl[0], gl[1], gl[2], gl[3], gl[4], gl[5], gl[6], gl[7], gl[8], gl[9], gl[10], gl[11],
        s_ws, out, nrows_gl);
}

// Round 3
// 195.277 us; speedup vs baseline: 13.6414x; 13.6414x over previous
//
#include <hip/hip_runtime.h>
#include <hip/hip_bf16.h>
#include <math.h>

#define HID 64
#define NBASES 8
#define BATCH 2048
#define NPAIRS 120
#define XCOLS 921

#define COL_Z 0
#define COL_D 64
#define COL_INVD 184
#define COL_INVSQ 304
#define COL_EXPD 424
#define COL_SCR 544
#define COL_LOGD 664
#define COL_PW 784
#define COL_ND 904
#define COL_GL 920

typedef __attribute__((ext_vector_type(8))) short bf16x8;
typedef __attribute__((ext_vector_type(4))) float f32x4;

__device__ __forceinline__ float fast_rcp(float x) { return __builtin_amdgcn_rcpf(x); }
__device__ __forceinline__ float silu_f(float x) { return x * fast_rcp(1.0f + __expf(-x)); }
__device__ __forceinline__ unsigned short f2b(float f) {
    __hip_bfloat16 h = __float2bfloat16(f);
    return __builtin_bit_cast(unsigned short, h);
}

// ---------------- sel gate ----------------
__global__ __launch_bounds__(64) void sel_kernel(
    const float* __restrict__ z,
    const float* __restrict__ W1, const float* __restrict__ b1,
    const float* __restrict__ W2, const float* __restrict__ b2,
    const float* __restrict__ W3, const float* __restrict__ b3,
    float* __restrict__ s_out)
{
    int b = blockIdx.x;
    int t = threadIdx.x;
    __shared__ float zs[64];
    __shared__ float h1[64];
    __shared__ float h2[32];
    zs[t] = z[b * 64 + t];
    __syncthreads();
    {
        float acc = b1[t];
        #pragma unroll
        for (int i = 0; i < 64; ++i) acc += zs[i] * W1[i * 64 + t];
        h1[t] = silu_f(acc);
    }
    __syncthreads();
    if (t < 32) {
        float acc = b2[t];
        #pragma unroll
        for (int i = 0; i < 64; ++i) acc += h1[i] * W2[i * 32 + t];
        h2[t] = silu_f(acc);
    }
    __syncthreads();
    if (t == 0) {
        float acc = b3[0];
        #pragma unroll
        for (int i = 0; i < 32; ++i) acc += h2[i] * W3[i];
        s_out[b] = fast_rcp(1.0f + __expf(-acc));
    }
}

// ---------------- geometry features + gated z columns ----------------
__global__ __launch_bounds__(128) void geom_kernel(
    const float* __restrict__ z, const float* __restrict__ s_gate,
    float* __restrict__ out)
{
    int b = blockIdx.x;
    int t = threadIdx.x;
    __shared__ float zs[64];
    if (t < 64) zs[t] = z[b * 64 + t];
    __syncthreads();
    float s = s_gate[b];
    float* row = out + (size_t)b * XCOLS;
    if (t < 64) {
        float v = zs[t] * s;
        row[COL_Z + t] = fminf(fmaxf(v, -1e6f), 1e6f);
    }
    if (t < NPAIRS) {
        int p = t;
        int i = 0, pp = p;
        while (pp >= 15 - i) { pp -= 15 - i; ++i; }
        int j = i + 1 + pp;
        float dx = zs[i * 4 + 0] - zs[j * 4 + 0];
        float dy = zs[i * 4 + 1] - zs[j * 4 + 1];
        float d = sqrtf(dx * dx + dy * dy);
        d = fmaxf(d, 0.001f);
        float inv_d = fast_rcp(d + 0.1f);
        float inv_sq = fast_rcp(d * d + 0.1f);
        float exp_d = __expf(-fminf(d, 20.0f));
        float screened = exp_d * inv_d;
        float log_d = __logf(d + 1.0f);
        row[COL_D + p] = d * s;
        row[COL_INVD + p] = inv_d * s;
        row[COL_INVSQ + p] = inv_sq * s;
        row[COL_EXPD + p] = exp_d * s;
        row[COL_SCR + p] = screened * s;
        row[COL_LOGD + p] = log_d * s;
    }
}

// ---------------- MFMA basis kernel ----------------
// Block: 256 threads = 4 waves; 64 rows per block (16 per wave); 8 bases sequential.
// MODE 0 = pw (DIN=8), 1 = nd (DIN=4), 2 = gl (DIN=64)
template<int DIN, int MODE>
__global__ __launch_bounds__(256) void basis_mfma_kernel(
    const float* __restrict__ z,
    const float* __restrict__ W1g, const float* __restrict__ b1g,
    const float* __restrict__ W2g, const float* __restrict__ b2g,
    const float* __restrict__ W3g, const float* __restrict__ b3g,
    const float* __restrict__ scaleg,
    const float* __restrict__ aW1, const float* __restrict__ ab1,
    const float* __restrict__ aW2, const float* __restrict__ ab2,
    const float* __restrict__ resg,
    const float* __restrict__ s_gate,
    float* __restrict__ out)
{
    constexpr int NXF = (DIN > 8) ? 2 : 1;  // X k-fragments

    __shared__ __align__(16) unsigned short W2t[2][64 * 64]; // transposed, bf16, swizzled, dbuf
    __shared__ __align__(16) unsigned short H1s[4][16 * 64]; // per-wave silu(h1), bf16, swizzled
    __shared__ float AttS[64][9];  // att*scale, padded stride
    __shared__ float tailS[64];    // res*mean + sum att*scale*b3

    const int tid = threadIdx.x;
    const int lane = tid & 63;
    const int wave = tid >> 6;
    const int g = lane >> 4;     // 0..3 (k-group)
    const int lo = lane & 15;
    const int row0 = blockIdx.x * 64;

    // ---- X fragment (B operand of H1^T mfma): basis-invariant, held in regs ----
    bf16x8 xfrag[NXF];
    {
        int myrow = row0 + wave * 16 + lo;
        if (MODE == 2) {
            const float* zb = z + (size_t)myrow * 64;
            #pragma unroll
            for (int kb = 0; kb < NXF; ++kb) {
                union { bf16x8 v; unsigned short u[8]; } fr;
                #pragma unroll
                for (int e = 0; e < 8; ++e) fr.u[e] = f2b(zb[kb * 32 + g * 8 + e]);
                xfrag[kb] = fr.v;
            }
        } else {
            union { bf16x8 v; unsigned short u[8]; } fr;
            #pragma unroll
            for (int e = 0; e < 8; ++e) fr.u[e] = 0;
            if (g == 0) {
                if (MODE == 0) {
                    unsigned int b = (unsigned)myrow / 120u;
                    int pp = myrow - (int)b * 120;
                    int i = 0;
                    while (pp >= 15 - i) { pp -= 15 - i; ++i; }
                    int j = i + 1 + pp;
                    const float* zb = z + b * 64;
                    #pragma unroll
                    for (int q = 0; q < 4; ++q) fr.u[q] = f2b(zb[i * 4 + q]);
                    #pragma unroll
                    for (int q = 0; q < 4; ++q) fr.u[4 + q] = f2b(zb[j * 4 + q]);
                } else {
                    unsigned int b = (unsigned)myrow >> 4;
                    int node = myrow & 15;
                    const float* zb = z + b * 64 + node * 4;
                    #pragma unroll
                    for (int q = 0; q < 4; ++q) fr.u[q] = f2b(zb[q]);
                }
            }
            xfrag[0] = fr.v;
        }
    }

    // ---- prologue: issue W2(basis 0) loads, then attention (threads<64), then stage ----
    float wv[16];
    {
        const int col = tid & 63, kg = tid >> 6;
        const float* src = W2g; // basis 0
        #pragma unroll
        for (int kk = 0; kk < 16; ++kk) wv[kk] = src[(kg * 16 + kk) * 64 + col];
    }

    if (tid < 64) {
        int myrow = row0 + tid;
        float x[DIN];
        if (MODE == 0) {
            unsigned int b = (unsigned)myrow / 120u;
            int pp = myrow - (int)b * 120;
            int i = 0;
            while (pp >= 15 - i) { pp -= 15 - i; ++i; }
            int j = i + 1 + pp;
            const float* zb = z + b * 64;
            #pragma unroll
            for (int q = 0; q < 4; ++q) { x[q] = zb[i * 4 + q]; x[4 + q] = zb[j * 4 + q]; }
        } else if (MODE == 1) {
            unsigned int b = (unsigned)myrow >> 4;
            int node = myrow & 15;
            const float* zb = z + b * 64 + node * 4;
            #pragma unroll
            for (int q = 0; q < 4; ++q) x[q] = zb[q];
        } else {
            const float* zb = z + (size_t)myrow * 64;
            #pragma unroll
            for (int q = 0; q < 64; ++q) x[q] = zb[q];
        }
        float a1[32];
        #pragma unroll
        for (int jj = 0; jj < 32; ++jj) {
            float acc = ab1[jj];
            #pragma unroll
            for (int ii = 0; ii < DIN; ++ii) acc += x[ii] * aW1[ii * 32 + jj];
            a1[jj] = silu_f(acc);
        }
        float lg[8];
        #pragma unroll
        for (int n = 0; n < 8; ++n) {
            float acc = ab2[n];
            #pragma unroll
            for (int jj = 0; jj < 32; ++jj) acc += a1[jj] * aW2[jj * 8 + n];
            lg[n] = acc;
        }
        float m = lg[0];
        #pragma unroll
        for (int n = 1; n < 8; ++n) m = fmaxf(m, lg[n]);
        float sum = 0.f;
        #pragma unroll
        for (int n = 0; n < 8; ++n) { lg[n] = __expf(lg[n] - m); sum += lg[n]; }
        float inv = fast_rcp(sum);
        float tail = 0.f;
        #pragma unroll
        for (int n = 0; n < 8; ++n) {
            float as_ = lg[n] * inv * scaleg[n];
            AttS[tid][n] = as_;
            tail += as_ * b3g[n];
        }
        float mean = 0.f;
        #pragma unroll
        for (int ii = 0; ii < DIN; ++ii) mean += x[ii];
        tail += resg[0] * (mean * (1.0f / (float)DIN));
        tailS[tid] = tail;
    }

    // stage W2t[0]
    {
        const int col = tid & 63, kg = tid >> 6;
        union { bf16x8 v; unsigned short u[8]; } w0, w1;
        #pragma unroll
        for (int kk = 0; kk < 8; ++kk) { w0.u[kk] = f2b(wv[kk]); w1.u[kk] = f2b(wv[8 + kk]); }
        int base = col * 64 + kg * 16;
        int sw = (col & 7) << 3;
        *(bf16x8*)&W2t[0][(base) ^ sw] = w0.v;
        *(bf16x8*)&W2t[0][(base + 8) ^ sw] = w1.v;
    }
    __syncthreads();

    const int losw = (lo & 7) << 3;
    f32x4 zeroacc = {0.f, 0.f, 0.f, 0.f};
    float outacc[4] = {0.f, 0.f, 0.f, 0.f};

    for (int n = 0; n < NBASES; ++n) {
        const int cur = n & 1;
        // prefetch next basis W2 into regs (T14 async split)
        if (n < NBASES - 1) {
            const int col = tid & 63, kg = tid >> 6;
            const float* src = W2g + (n + 1) * 4096;
            #pragma unroll
            for (int kk = 0; kk < 16; ++kk) wv[kk] = src[(kg * 16 + kk) * 64 + col];
        }

        // ---- H1^T = W1^T * X^T via mfma; write silu(h1) to per-wave LDS ----
        const float* W1n = W1g + n * DIN * 64;
        const float* b1n = b1g + n * 64;
        #pragma unroll
        for (int mt = 0; mt < 4; ++mt) {
            f32x4 d = zeroacc;
            if (DIN <= 8) {
                union { bf16x8 v; unsigned short u[8]; } fa;
                #pragma unroll
                for (int e = 0; e < 8; ++e) fa.u[e] = 0;
                if (g == 0) {
                    #pragma unroll
                    for (int e = 0; e < DIN; ++e) fa.u[e] = f2b(W1n[e * 64 + mt * 16 + lo]);
                }
                d = __builtin_amdgcn_mfma_f32_16x16x32_bf16(fa.v, xfrag[0], d, 0, 0, 0);
            } else {
                #pragma unroll
                for (int kb = 0; kb < NXF; ++kb) {
                    union { bf16x8 v; unsigned short u[8]; } fa;
                    #pragma unroll
                    for (int e = 0; e < 8; ++e)
                        fa.u[e] = f2b(W1n[(kb * 32 + g * 8 + e) * 64 + mt * 16 + lo]);
                    d = __builtin_amdgcn_mfma_f32_16x16x32_bf16(fa.v, xfrag[kb], d, 0, 0, 0);
                }
            }
            int h1c = mt * 16 + g * 4;
            float s0 = silu_f(d[0] + b1n[h1c + 0]);
            float s1 = silu_f(d[1] + b1n[h1c + 1]);
            float s2 = silu_f(d[2] + b1n[h1c + 2]);
            float s3 = silu_f(d[3] + b1n[h1c + 3]);
            unsigned int p0 = (unsigned int)f2b(s0) | ((unsigned int)f2b(s1) << 16);
            unsigned int p1 = (unsigned int)f2b(s2) | ((unsigned int)f2b(s3) << 16);
            int eidx = (lo * 64 + h1c) ^ losw;
            *(uint2*)&H1s[wave][eidx] = make_uint2(p0, p1);
        }
        __syncthreads();  // H1s + keep waves aligned on W2t buffers

        // ---- H2 = H1 * W2 via mfma + epilogue ----
        bf16x8 afr0 = *(const bf16x8*)&H1s[wave][(lo * 64 + 0 + g * 8) ^ losw];
        bf16x8 afr1 = *(const bf16x8*)&H1s[wave][(lo * 64 + 32 + g * 8) ^ losw];
        const float* b2n = b2g + n * 64;
        const float* W3n = W3g + n * 64;
        float part[4] = {0.f, 0.f, 0.f, 0.f};
        #pragma unroll
        for (int cb = 0; cb < 4; ++cb) {
            int col = cb * 16 + lo;
            int csw = (col & 7) << 3;
            bf16x8 bf0 = *(const bf16x8*)&W2t[cur][(col * 64 + 0 + g * 8) ^ csw];
            bf16x8 bf1 = *(const bf16x8*)&W2t[cur][(col * 64 + 32 + g * 8) ^ csw];
            f32x4 acc = zeroacc;
            acc = __builtin_amdgcn_mfma_f32_16x16x32_bf16(afr0, bf0, acc, 0, 0, 0);
            acc = __builtin_amdgcn_mfma_f32_16x16x32_bf16(afr1, bf1, acc, 0, 0, 0);
            float b2v = b2n[col];
            float w3v = W3n[col];
            #pragma unroll
            for (int r = 0; r < 4; ++r) part[r] += silu_f(acc[r] + b2v) * w3v;
        }
        #pragma unroll
        for (int r = 0; r < 4; ++r) {
            int row_l = wave * 16 + g * 4 + r;
            outacc[r] += AttS[row_l][n] * part[r];
        }

        // write prefetched W2 -> other buffer
        if (n < NBASES - 1) {
            const int col = tid & 63, kg = tid >> 6;
            union { bf16x8 v; unsigned short u[8]; } w0, w1;
            #pragma unroll
            for (int kk = 0; kk < 8; ++kk) { w0.u[kk] = f2b(wv[kk]); w1.u[kk] = f2b(wv[8 + kk]); }
            int base = col * 64 + kg * 16;
            int sw = (col & 7) << 3;
            *(bf16x8*)&W2t[cur ^ 1][(base) ^ sw] = w0.v;
            *(bf16x8*)&W2t[cur ^ 1][(base + 8) ^ sw] = w1.v;
        }
        __syncthreads();
    }

    // ---- reduce across the 16 lanes holding different h2-cols, store ----
    #pragma unroll
    for (int r = 0; r < 4; ++r) {
        float v = outacc[r];
        v += __shfl_xor(v, 1);
        v += __shfl_xor(v, 2);
        v += __shfl_xor(v, 4);
        v += __shfl_xor(v, 8);
        if (lo == 0) {
            int row_l = wave * 16 + g * 4 + r;
            int rg = row0 + row_l;
            unsigned int b;
            int colo;
            if (MODE == 0) {
                b = (unsigned)rg / 120u;
                colo = COL_PW + (rg - (int)b * 120);
            } else if (MODE == 1) {
                b = (unsigned)rg >> 4;
                colo = COL_ND + (rg & 15);
            } else {
                b = (unsigned)rg;
                colo = COL_GL;
            }
            float o = (v + tailS[row_l]) * s_gate[b];
            o = fminf(fmaxf(o, -1e6f), 1e6f);
            out[(size_t)b * XCOLS + colo] = o;
        }
    }
}

extern "C" void kernel_launch(void* const* d_in, const int* in_sizes, int n_in,
                              void* d_out, int out_size, void* d_ws, size_t ws_size,
                              hipStream_t stream) {
    const float* z = (const float*)d_in[0];
    const float* pw[12]; const float* nd[12]; const float* gl[12];
    for (int i = 0; i < 12; ++i) pw[i] = (const float*)d_in[1 + i];
    for (int i = 0; i < 12; ++i) nd[i] = (const float*)d_in[13 + i];
    for (int i = 0; i < 12; ++i) gl[i] = (const float*)d_in[25 + i];
    const float* sel_W1 = (const float*)d_in[37];
    const float* sel_b1 = (const float*)d_in[38];
    const float* sel_W2 = (const float*)d_in[39];
    const float* sel_b2 = (const float*)d_in[40];
    const float* sel_W3 = (const float*)d_in[41];
    const float* sel_b3 = (const float*)d_in[42];

    float* out = (float*)d_out;
    float* s_ws = (float*)d_ws;

    sel_kernel<<<BATCH, 64, 0, stream>>>(z, sel_W1, sel_b1, sel_W2, sel_b2, sel_W3, sel_b3, s_ws);
    geom_kernel<<<BATCH, 128, 0, stream>>>(z, s_ws, out);

    basis_mfma_kernel<8, 0><<<(BATCH * NPAIRS) / 64, 256, 0, stream>>>(
        z, pw[0], pw[1], pw[2], pw[3], pw[4], pw[5], pw[6], pw[7], pw[8], pw[9], pw[10], pw[11],
        s_ws, out);

    basis_mfma_kernel<4, 1><<<(BATCH * 16) / 64, 256, 0, stream>>>(
        z, nd[0], nd[1], nd[2], nd[3], nd[4], nd[5], nd[6], nd[7], nd[8], nd[9], nd[10], nd[11],
        s_ws, out);

    basis_mfma_kernel<64, 2><<<BATCH / 64, 256, 0, stream>>>(
        z, gl[0], gl[1], gl[2], gl[3], gl[4], gl[5], gl[6], gl[7], gl[8], gl[9], gl[10], gl[11],
        s_ws, out);
}

// Round 4
// 162.359 us; speedup vs baseline: 16.4071x; 1.2027x over previous
//
#include <hip/hip_runtime.h>
#include <hip/hip_bf16.h>
#include <math.h>

#define XCOLS 921
#define COL_Z 0
#define COL_D 64
#define COL_INVD 184
#define COL_INVSQ 304
#define COL_EXPD 424
#define COL_SCR 544
#define COL_LOGD 664
#define COL_PW 784
#define COL_ND 904
#define COL_GL 920

#define BATCH 2048
#define NPAIRS 120
#define PW_BLOCKS 3840   // 2048*120/64
#define ND_BLOCKS 512    // 2048*16/64
#define GL_BLOCKS 32     // 2048/64

typedef unsigned short ushort_t;
typedef __attribute__((ext_vector_type(8))) short bf16x8;
typedef __attribute__((ext_vector_type(4))) float f32x4;

// ---- d_ws layout (bytes) ----
#define WS_SGATE   0        // 2048 f32
#define WS_PWW1T   8192     // [8][64][8]  bf16 (4096)
#define WS_NDW1T   16384    // [8][64][8]  bf16
#define WS_GLW1T   24576    // [8][64][64] bf16 (32768)
#define WS_PWW2T   90112    // [8][8][64][8] bf16 (32768)
#define WS_NDW2T   155648
#define WS_GLW2T   221184
#define WS_PWBW3   286720   // [8][64] float2
#define WS_NDBW3   290816
#define WS_GLBW3   294912

__device__ __forceinline__ float fast_rcp(float x) { return __builtin_amdgcn_rcpf(x); }
__device__ __forceinline__ float silu_f(float x) { return x * fast_rcp(1.0f + __expf(-x)); }
__device__ __forceinline__ ushort_t f2b(float f) {
    __hip_bfloat16 h = __float2bfloat16(f);
    return __builtin_bit_cast(ushort_t, h);
}

struct BArgs {
    const ushort_t* W1t;   // [8][64][8] bf16
    const ushort_t* W2t;   // [8][8kb][64col][8e] bf16
    const float2*   bw3;   // [8][64] {b2, W3}
    const float *b1, *b3, *scale, *aW1, *ab1, *aW2, *ab2, *res;
};

// ================= prep: convert weights to bf16 fragment layouts =================
__global__ __launch_bounds__(256) void prep_kernel(
    const float* __restrict__ pwW1, const float* __restrict__ ndW1, const float* __restrict__ glW1,
    const float* __restrict__ pwW2, const float* __restrict__ ndW2, const float* __restrict__ glW2,
    const float* __restrict__ pwb2, const float* __restrict__ pwW3,
    const float* __restrict__ ndb2, const float* __restrict__ ndW3,
    const float* __restrict__ glb2, const float* __restrict__ glW3,
    char* __restrict__ ws)
{
    ushort_t* pwW1t = (ushort_t*)(ws + WS_PWW1T);
    ushort_t* ndW1t = (ushort_t*)(ws + WS_NDW1T);
    ushort_t* glW1t = (ushort_t*)(ws + WS_GLW1T);
    ushort_t* pwW2t = (ushort_t*)(ws + WS_PWW2T);
    ushort_t* ndW2t = (ushort_t*)(ws + WS_NDW2T);
    ushort_t* glW2t = (ushort_t*)(ws + WS_GLW2T);
    float2* pwBW3 = (float2*)(ws + WS_PWBW3);
    float2* ndBW3 = (float2*)(ws + WS_NDBW3);
    float2* glBW3 = (float2*)(ws + WS_GLBW3);

    int tid0 = blockIdx.x * 256 + threadIdx.x;
    int stride = gridDim.x * 256;

    // seg A: pw/nd W1t, [n][m][k8], 2 x 4096
    for (int t = tid0; t < 8192; t += stride) {
        int u = t & 4095;
        int n = u >> 9, m = (u >> 3) & 63, k = u & 7;
        if (t < 4096) pwW1t[u] = f2b(pwW1[n * 512 + k * 64 + m]);
        else          ndW1t[u] = (k < 4) ? f2b(ndW1[n * 256 + k * 64 + m]) : (ushort_t)0;
    }
    // seg B: gl W1t [n][m][k64]
    for (int t = tid0; t < 32768; t += stride) {
        int n = t >> 12, m = (t >> 6) & 63, k = t & 63;
        glW1t[t] = f2b(glW1[n * 4096 + k * 64 + m]);
    }
    // seg C: W2t [n][kb][col][e], 3 x 32768
    for (int t = tid0; t < 3 * 32768; t += stride) {
        int which = t >> 15;
        int u = t & 32767;
        int n = u >> 12, kb = (u >> 9) & 7, col = (u >> 3) & 63, e = u & 7;
        int k = (kb & 3) * 8 + e + ((kb >> 2) << 5);
        const float* src = (which == 0) ? pwW2 : (which == 1) ? ndW2 : glW2;
        ushort_t* dst = (which == 0) ? pwW2t : (which == 1) ? ndW2t : glW2t;
        dst[u] = f2b(src[n * 4096 + k * 64 + col]);
    }
    // seg D: packed {b2, W3}
    for (int t = tid0; t < 3 * 512; t += stride) {
        int which = t >> 9;
        int u = t & 511;
        const float* b2 = (which == 0) ? pwb2 : (which == 1) ? ndb2 : glb2;
        const float* W3 = (which == 0) ? pwW3 : (which == 1) ? ndW3 : glW3;
        float2* dst = (which == 0) ? pwBW3 : (which == 1) ? ndBW3 : glBW3;
        dst[u] = make_float2(b2[u], W3[u]);
    }
}

// ================= fused sel gate + geometry =================
__global__ __launch_bounds__(64) void selgeom_kernel(
    const float* __restrict__ z,
    const float* __restrict__ W1, const float* __restrict__ b1,
    const float* __restrict__ W2, const float* __restrict__ b2,
    const float* __restrict__ W3, const float* __restrict__ b3,
    float* __restrict__ s_out, float* __restrict__ out)
{
    int b = blockIdx.x;
    int t = threadIdx.x;
    __shared__ float zs[64];
    __shared__ float h1[64];
    __shared__ float h2[32];
    __shared__ float sg;
    zs[t] = z[b * 64 + t];
    __syncthreads();
    {
        float acc = b1[t];
        #pragma unroll
        for (int i = 0; i < 64; ++i) acc += zs[i] * W1[i * 64 + t];
        h1[t] = silu_f(acc);
    }
    __syncthreads();
    if (t < 32) {
        float acc = b2[t];
        #pragma unroll
        for (int i = 0; i < 64; ++i) acc += h1[i] * W2[i * 32 + t];
        h2[t] = silu_f(acc);
    }
    __syncthreads();
    if (t == 0) {
        float acc = b3[0];
        #pragma unroll
        for (int i = 0; i < 32; ++i) acc += h2[i] * W3[i];
        float s = fast_rcp(1.0f + __expf(-acc));
        sg = s;
        s_out[b] = s;
    }
    __syncthreads();
    float s = sg;
    float* row = out + (size_t)b * XCOLS;
    {
        float v = zs[t] * s;
        row[COL_Z + t] = fminf(fmaxf(v, -1e6f), 1e6f);
    }
    #pragma unroll
    for (int rep = 0; rep < 2; ++rep) {
        int p = t + rep * 64;
        if (p < NPAIRS) {
            int i = 0, pp = p;
            while (pp >= 15 - i) { pp -= 15 - i; ++i; }
            int j = i + 1 + pp;
            float dx = zs[i * 4 + 0] - zs[j * 4 + 0];
            float dy = zs[i * 4 + 1] - zs[j * 4 + 1];
            float d = sqrtf(dx * dx + dy * dy);
            d = fmaxf(d, 0.001f);
            float inv_d = fast_rcp(d + 0.1f);
            float inv_sq = fast_rcp(d * d + 0.1f);
            float exp_d = __expf(-fminf(d, 20.0f));
            float screened = exp_d * inv_d;
            float log_d = __logf(d + 1.0f);
            row[COL_D + p] = d * s;
            row[COL_INVD + p] = inv_d * s;
            row[COL_INVSQ + p] = inv_sq * s;
            row[COL_EXPD + p] = exp_d * s;
            row[COL_SCR + p] = screened * s;
            row[COL_LOGD + p] = log_d * s;
        }
    }
}

// ================= pw+nd basis kernel (merged) =================
__global__ __launch_bounds__(256, 4) void basis2_kernel(
    const float* __restrict__ z, BArgs apw, BArgs andp,
    const float* __restrict__ s_gate, float* __restrict__ out)
{
    __shared__ ushort_t pairT[128];
    __shared__ float lgp[4][64][9];
    __shared__ float AttS[64][9];
    __shared__ float meanS[64];
    __shared__ float tailS[64];
    __shared__ uint H1u[2][4][576];   // per-wave 16 rows x 36 dwords (pad +4)

    const int tid = threadIdx.x;
    const int lane = tid & 63;
    const int wave = tid >> 6;
    const int g = lane >> 4;
    const int lo = lane & 15;

    const bool isnd = (blockIdx.x >= PW_BLOCKS);
    const int rowbase = isnd ? (blockIdx.x - PW_BLOCKS) * 64 : blockIdx.x * 64;
    const BArgs A = isnd ? andp : apw;

    if (!isnd && tid < NPAIRS) {
        int p = tid, i = 0, pp = p;
        while (pp >= 15 - i) { pp -= 15 - i; ++i; }
        int j = i + 1 + pp;
        pairT[tid] = (ushort_t)((i * 4) | ((j * 4) << 8));
    }
    __syncthreads();

    // ---- attention partials (4-way split across waves) + mean ----
    {
        int r = tid & 63;
        int rloc = rowbase + r;
        float x[8];
        if (!isnd) {
            unsigned bb = (unsigned)rloc / 120u;
            int p = rloc - (int)bb * 120;
            ushort_t ij = pairT[p];
            const float* zb = z + bb * 64;
            int i4 = ij & 255, j4 = ij >> 8;
            #pragma unroll
            for (int q = 0; q < 4; ++q) { x[q] = zb[i4 + q]; x[4 + q] = zb[j4 + q]; }
        } else {
            unsigned bb = (unsigned)rloc >> 4;
            const float* zb = z + bb * 64 + (rloc & 15) * 4;
            #pragma unroll
            for (int q = 0; q < 4; ++q) { x[q] = zb[q]; x[4 + q] = 0.f; }
        }
        float part[8];
        #pragma unroll
        for (int n = 0; n < 8; ++n) part[n] = (wave == 0) ? A.ab2[n] : 0.f;
        #pragma unroll
        for (int u = 0; u < 8; ++u) {
            int unit = wave * 8 + u;
            float acc = A.ab1[unit];
            if (!isnd) {
                #pragma unroll
                for (int ii = 0; ii < 8; ++ii) acc += x[ii] * A.aW1[ii * 32 + unit];
            } else {
                #pragma unroll
                for (int ii = 0; ii < 4; ++ii) acc += x[ii] * A.aW1[ii * 32 + unit];
            }
            float a1u = silu_f(acc);
            #pragma unroll
            for (int n = 0; n < 8; ++n) part[n] += a1u * A.aW2[unit * 8 + n];
        }
        #pragma unroll
        for (int n = 0; n < 8; ++n) lgp[wave][r][n] = part[n];
        if (wave == 0) {
            float mean = x[0] + x[1] + x[2] + x[3];
            if (!isnd) mean += x[4] + x[5] + x[6] + x[7];
            meanS[r] = mean * (isnd ? 0.25f : 0.125f);
        }
    }

    // ---- x fragment (B operand), basis-invariant ----
    bf16x8 xfrag;
    {
        int myrow = rowbase + wave * 16 + lo;
        union { bf16x8 v; ushort_t u[8]; } fr;
        #pragma unroll
        for (int e = 0; e < 8; ++e) fr.u[e] = 0;
        if (g == 0) {
            if (!isnd) {
                unsigned bb = (unsigned)myrow / 120u;
                int p = myrow - (int)bb * 120;
                ushort_t ij = pairT[p];
                const float* zb = z + bb * 64;
                int i4 = ij & 255, j4 = ij >> 8;
                #pragma unroll
                for (int q = 0; q < 4; ++q) { fr.u[q] = f2b(zb[i4 + q]); fr.u[4 + q] = f2b(zb[j4 + q]); }
            } else {
                unsigned bb = (unsigned)myrow >> 4;
                const float* zb = z + bb * 64 + (myrow & 15) * 4;
                #pragma unroll
                for (int q = 0; q < 4; ++q) fr.u[q] = f2b(zb[q]);
            }
        }
        xfrag = fr.v;
    }
    __syncthreads();

    // ---- softmax finalize ----
    if (tid < 64) {
        float lg[8];
        #pragma unroll
        for (int n = 0; n < 8; ++n)
            lg[n] = lgp[0][tid][n] + lgp[1][tid][n] + lgp[2][tid][n] + lgp[3][tid][n];
        float m = lg[0];
        #pragma unroll
        for (int n = 1; n < 8; ++n) m = fmaxf(m, lg[n]);
        float sum = 0.f;
        #pragma unroll
        for (int n = 0; n < 8; ++n) { lg[n] = __expf(lg[n] - m); sum += lg[n]; }
        float inv = fast_rcp(sum);
        float tail = 0.f;
        #pragma unroll
        for (int n = 0; n < 8; ++n) {
            float as_ = lg[n] * inv * A.scale[n];
            AttS[tid][n] = as_;
            tail += as_ * A.b3[n];
        }
        tailS[tid] = tail + A.res[0] * meanS[tid];
    }
    __syncthreads();

    // ---- basis loop: no barriers (per-wave LDS relay, ping-pong) ----
    const int wr_base = lo * 36;
    float outacc[4] = {0.f, 0.f, 0.f, 0.f};
    for (int n = 0; n < 8; ++n) {
        const ushort_t* w1n = A.W1t + n * 512;
        uint* hb = &H1u[n & 1][wave][0];
        #pragma unroll
        for (int mt = 0; mt < 4; ++mt) {
            bf16x8 af;
            if (g == 0) af = *(const bf16x8*)&w1n[(mt * 16 + lo) * 8];
            else { bf16x8 zf = {0,0,0,0,0,0,0,0}; af = zf; }
            f32x4 d = {0.f, 0.f, 0.f, 0.f};
            d = __builtin_amdgcn_mfma_f32_16x16x32_bf16(af, xfrag, d, 0, 0, 0);
            float4 bb = *(const float4*)&A.b1[n * 64 + mt * 16 + g * 4];
            float s0 = silu_f(d[0] + bb.x);
            float s1 = silu_f(d[1] + bb.y);
            float s2 = silu_f(d[2] + bb.z);
            float s3 = silu_f(d[3] + bb.w);
            uint p0 = (uint)f2b(s0) | ((uint)f2b(s1) << 16);
            uint p1 = (uint)f2b(s2) | ((uint)f2b(s3) << 16);
            *(uint2*)&hb[wr_base + mt * 8 + g * 2] = make_uint2(p0, p1);
        }
        bf16x8 a0 = *(const bf16x8*)&hb[wr_base + 4 * g];
        bf16x8 a1v = *(const bf16x8*)&hb[wr_base + 16 + 4 * g];
        const ushort_t* w2n = A.W2t + n * 4096;
        float pv[4] = {0.f, 0.f, 0.f, 0.f};
        #pragma unroll
        for (int cb = 0; cb < 4; ++cb) {
            int col = cb * 16 + lo;
            bf16x8 bf0 = *(const bf16x8*)&w2n[(g * 64 + col) * 8];
            bf16x8 bf1 = *(const bf16x8*)&w2n[((g + 4) * 64 + col) * 8];
            f32x4 acc = {0.f, 0.f, 0.f, 0.f};
            acc = __builtin_amdgcn_mfma_f32_16x16x32_bf16(a0, bf0, acc, 0, 0, 0);
            acc = __builtin_amdgcn_mfma_f32_16x16x32_bf16(a1v, bf1, acc, 0, 0, 0);
            float2 bw = A.bw3[n * 64 + col];
            #pragma unroll
            for (int r = 0; r < 4; ++r) pv[r] += silu_f(acc[r] + bw.x) * bw.y;
        }
        #pragma unroll
        for (int r = 0; r < 4; ++r) outacc[r] += AttS[wave * 16 + g * 4 + r][n] * pv[r];
    }

    // ---- reduce over 16 h2-col lanes, store ----
    #pragma unroll
    for (int r = 0; r < 4; ++r) {
        float v = outacc[r];
        v += __shfl_xor(v, 1);
        v += __shfl_xor(v, 2);
        v += __shfl_xor(v, 4);
        v += __shfl_xor(v, 8);
        if (lo == 0) {
            int row_l = wave * 16 + g * 4 + r;
            int rg = rowbase + row_l;
            unsigned bb; int colo;
            if (!isnd) {
                bb = (unsigned)rg / 120u;
                colo = COL_PW + (rg - (int)bb * 120);
            } else {
                bb = (unsigned)rg >> 4;
                colo = COL_ND + (rg & 15);
            }
            float o = (v + tailS[row_l]) * s_gate[bb];
            o = fminf(fmaxf(o, -1e6f), 1e6f);
            out[(size_t)bb * XCOLS + colo] = o;
        }
    }
}

// ================= gl basis kernel (DIN=64) =================
__global__ __launch_bounds__(256, 2) void basis_gl_kernel(
    const float* __restrict__ z, BArgs A,
    const float* __restrict__ s_gate, float* __restrict__ out)
{
    __shared__ float zsh[64][65];
    __shared__ float lgp[4][64][9];
    __shared__ float AttS[64][9];
    __shared__ float meanS[64];
    __shared__ float tailS[64];
    __shared__ uint H1u[2][4][576];

    const int tid = threadIdx.x;
    const int lane = tid & 63;
    const int wave = tid >> 6;
    const int g = lane >> 4;
    const int lo = lane & 15;
    const int rowbase = blockIdx.x * 64;

    // stage z rows (coalesced)
    #pragma unroll
    for (int e = 0; e < 16; ++e) {
        int idx = e * 256 + tid;
        zsh[idx >> 6][idx & 63] = z[(size_t)rowbase * 64 + idx];
    }
    __syncthreads();

    // attention partials + mean
    {
        int r = tid & 63;
        float part[8];
        #pragma unroll
        for (int n = 0; n < 8; ++n) part[n] = (wave == 0) ? A.ab2[n] : 0.f;
        #pragma unroll
        for (int u = 0; u < 8; ++u) {
            int unit = wave * 8 + u;
            float acc = A.ab1[unit];
            for (int ii = 0; ii < 64; ++ii) acc += zsh[r][ii] * A.aW1[ii * 32 + unit];
            float a1u = silu_f(acc);
            #pragma unroll
            for (int n = 0; n < 8; ++n) part[n] += a1u * A.aW2[unit * 8 + n];
        }
        #pragma unroll
        for (int n = 0; n < 8; ++n) lgp[wave][r][n] = part[n];
        if (wave == 0) {
            float mean = 0.f;
            for (int ii = 0; ii < 64; ++ii) mean += zsh[r][ii];
            meanS[r] = mean * (1.0f / 64.0f);
        }
    }

    // x fragments (2 k-halves)
    bf16x8 xf0, xf1;
    {
        int rl = wave * 16 + lo;
        union { bf16x8 v; ushort_t u[8]; } fr0, fr1;
        #pragma unroll
        for (int e = 0; e < 8; ++e) {
            fr0.u[e] = f2b(zsh[rl][g * 8 + e]);
            fr1.u[e] = f2b(zsh[rl][32 + g * 8 + e]);
        }
        xf0 = fr0.v; xf1 = fr1.v;
    }
    __syncthreads();

    if (tid < 64) {
        float lg[8];
        #pragma unroll
        for (int n = 0; n < 8; ++n)
            lg[n] = lgp[0][tid][n] + lgp[1][tid][n] + lgp[2][tid][n] + lgp[3][tid][n];
        float m = lg[0];
        #pragma unroll
        for (int n = 1; n < 8; ++n) m = fmaxf(m, lg[n]);
        float sum = 0.f;
        #pragma unroll
        for (int n = 0; n < 8; ++n) { lg[n] = __expf(lg[n] - m); sum += lg[n]; }
        float inv = fast_rcp(sum);
        float tail = 0.f;
        #pragma unroll
        for (int n = 0; n < 8; ++n) {
            float as_ = lg[n] * inv * A.scale[n];
            AttS[tid][n] = as_;
            tail += as_ * A.b3[n];
        }
        tailS[tid] = tail + A.res[0] * meanS[tid];
    }
    __syncthreads();

    const int wr_base = lo * 36;
    float outacc[4] = {0.f, 0.f, 0.f, 0.f};
    for (int n = 0; n < 8; ++n) {
        const ushort_t* w1n = A.W1t + n * 4096;
        uint* hb = &H1u[n & 1][wave][0];
        #pragma unroll
        for (int mt = 0; mt < 4; ++mt) {
            bf16x8 af0 = *(const bf16x8*)&w1n[(mt * 16 + lo) * 64 + g * 8];
            bf16x8 af1 = *(const bf16x8*)&w1n[(mt * 16 + lo) * 64 + 32 + g * 8];
            f32x4 d = {0.f, 0.f, 0.f, 0.f};
            d = __builtin_amdgcn_mfma_f32_16x16x32_bf16(af0, xf0, d, 0, 0, 0);
            d = __builtin_amdgcn_mfma_f32_16x16x32_bf16(af1, xf1, d, 0, 0, 0);
            float4 bb = *(const float4*)&A.b1[n * 64 + mt * 16 + g * 4];
            float s0 = silu_f(d[0] + bb.x);
            float s1 = silu_f(d[1] + bb.y);
            float s2 = silu_f(d[2] + bb.z);
            float s3 = silu_f(d[3] + bb.w);
            uint p0 = (uint)f2b(s0) | ((uint)f2b(s1) << 16);
            uint p1 = (uint)f2b(s2) | ((uint)f2b(s3) << 16);
            *(uint2*)&hb[wr_base + mt * 8 + g * 2] = make_uint2(p0, p1);
        }
        bf16x8 a0 = *(const bf16x8*)&hb[wr_base + 4 * g];
        bf16x8 a1v = *(const bf16x8*)&hb[wr_base + 16 + 4 * g];
        const ushort_t* w2n = A.W2t + n * 4096;
        float pv[4] = {0.f, 0.f, 0.f, 0.f};
        #pragma unroll
        for (int cb = 0; cb < 4; ++cb) {
            int col = cb * 16 + lo;
            bf16x8 bf0 = *(const bf16x8*)&w2n[(g * 64 + col) * 8];
            bf16x8 bf1 = *(const bf16x8*)&w2n[((g + 4) * 64 + col) * 8];
            f32x4 acc = {0.f, 0.f, 0.f, 0.f};
            acc = __builtin_amdgcn_mfma_f32_16x16x32_bf16(a0, bf0, acc, 0, 0, 0);
            acc = __builtin_amdgcn_mfma_f32_16x16x32_bf16(a1v, bf1, acc, 0, 0, 0);
            float2 bw = A.bw3[n * 64 + col];
            #pragma unroll
            for (int r = 0; r < 4; ++r) pv[r] += silu_f(acc[r] + bw.x) * bw.y;
        }
        #pragma unroll
        for (int r = 0; r < 4; ++r) outacc[r] += AttS[wave * 16 + g * 4 + r][n] * pv[r];
    }

    #pragma unroll
    for (int r = 0; r < 4; ++r) {
        float v = outacc[r];
        v += __shfl_xor(v, 1);
        v += __shfl_xor(v, 2);
        v += __shfl_xor(v, 4);
        v += __shfl_xor(v, 8);
        if (lo == 0) {
            int row_l = wave * 16 + g * 4 + r;
            int bb = rowbase + row_l;
            float o = (v + tailS[row_l]) * s_gate[bb];
            o = fminf(fmaxf(o, -1e6f), 1e6f);
            out[(size_t)bb * XCOLS + COL_GL] = o;
        }
    }
}

extern "C" void kernel_launch(void* const* d_in, const int* in_sizes, int n_in,
                              void* d_out, int out_size, void* d_ws, size_t ws_size,
                              hipStream_t stream) {
    const float* z = (const float*)d_in[0];
    const float* pw[12]; const float* nd[12]; const float* gl[12];
    for (int i = 0; i < 12; ++i) pw[i] = (const float*)d_in[1 + i];
    for (int i = 0; i < 12; ++i) nd[i] = (const float*)d_in[13 + i];
    for (int i = 0; i < 12; ++i) gl[i] = (const float*)d_in[25 + i];
    const float* sel_W1 = (const float*)d_in[37];
    const float* sel_b1 = (const float*)d_in[38];
    const float* sel_W2 = (const float*)d_in[39];
    const float* sel_b2 = (const float*)d_in[40];
    const float* sel_W3 = (const float*)d_in[41];
    const float* sel_b3 = (const float*)d_in[42];

    float* out = (float*)d_out;
    char* ws = (char*)d_ws;
    float* s_ws = (float*)(ws + WS_SGATE);

    prep_kernel<<<128, 256, 0, stream>>>(
        pw[0], nd[0], gl[0], pw[2], nd[2], gl[2],
        pw[3], pw[4], nd[3], nd[4], gl[3], gl[4], ws);

    selgeom_kernel<<<BATCH, 64, 0, stream>>>(
        z, sel_W1, sel_b1, sel_W2, sel_b2, sel_W3, sel_b3, s_ws, out);

    // arg structs (W1,b1,W2,b2,W3,b3,scale,aW1,ab1,aW2,ab2,res = idx 0..11)
    BArgs apw, andp, agl;
    apw.W1t = (const ushort_t*)(ws + WS_PWW1T);
    apw.W2t = (const ushort_t*)(ws + WS_PWW2T);
    apw.bw3 = (const float2*)(ws + WS_PWBW3);
    apw.b1 = pw[1]; apw.b3 = pw[5]; apw.scale = pw[6];
    apw.aW1 = pw[7]; apw.ab1 = pw[8]; apw.aW2 = pw[9]; apw.ab2 = pw[10]; apw.res = pw[11];

    andp.W1t = (const ushort_t*)(ws + WS_NDW1T);
    andp.W2t = (const ushort_t*)(ws + WS_NDW2T);
    andp.bw3 = (const float2*)(ws + WS_NDBW3);
    andp.b1 = nd[1]; andp.b3 = nd[5]; andp.scale = nd[6];
    andp.aW1 = nd[7]; andp.ab1 = nd[8]; andp.aW2 = nd[9]; andp.ab2 = nd[10]; andp.res = nd[11];

    agl.W1t = (const ushort_t*)(ws + WS_GLW1T);
    agl.W2t = (const ushort_t*)(ws + WS_GLW2T);
    agl.bw3 = (const float2*)(ws + WS_GLBW3);
    agl.b1 = gl[1]; agl.b3 = gl[5]; agl.scale = gl[6];
    agl.aW1 = gl[7]; agl.ab1 = gl[8]; agl.aW2 = gl[9]; agl.ab2 = gl[10]; agl.res = gl[11];

    basis2_kernel<<<PW_BLOCKS + ND_BLOCKS, 256, 0, stream>>>(z, apw, andp, s_ws, out);
    basis_gl_kernel<<<GL_BLOCKS, 256, 0, stream>>>(z, agl, s_ws, out);
}

// Round 5
// 137.143 us; speedup vs baseline: 19.4238x; 1.1839x over previous
//
#include <hip/hip_runtime.h>
#include <hip/hip_bf16.h>
#include <math.h>

#define XCOLS 921
#define COL_Z 0
#define COL_D 64
#define COL_INVD 184
#define COL_INVSQ 304
#define COL_EXPD 424
#define COL_SCR 544
#define COL_LOGD 664
#define COL_PW 784
#define COL_ND 904
#define COL_GL 920

#define BATCH 2048
#define NPAIRS 120
#define RPW (BATCH * NPAIRS)       /* 245760 */
#define RND (BATCH * 16)           /* 32768  */
#define RGL BATCH                  /* 2048   */
#define RTOT (RPW + RND + RGL)     /* 280576 */

#define PW_BLK 3840
#define ND_BLK 512
#define GL_BLK 32

// ---- d_ws byte offsets (total ~14.4 MB) ----
#define WS_SGATE   0u
#define WS_ZERO    8192u
#define WS_B1D_PW  8448u
#define WS_B1D_ND  10496u
#define WS_B1D_GL  12544u
#define WS_BW3_PW  14592u
#define WS_BW3_ND  18688u
#define WS_BW3_GL  22784u
#define WS_W1T_PW  26880u
#define WS_W1T_ND  35072u
#define WS_W1T_GL  43264u
#define WS_W2T_PW  108800u
#define WS_W2T_ND  174336u
#define WS_W2T_GL  239872u
#define WS_XF      305408u                  /* (RPW+RND) x 16B bf16x8 */
#define WS_XGL     4761856u                 /* RGL x 128B             */
#define WS_ATT     5024000u                 /* RTOT x 32B f32x8       */
#define WS_TAIL    14002432u                /* RTOT x 4B              */

typedef unsigned short ushort_t;
typedef unsigned int uint_t;
typedef __attribute__((ext_vector_type(8))) short bf16x8;
typedef __attribute__((ext_vector_type(4))) float f32x4;

__device__ __forceinline__ float fast_rcp(float x) { return __builtin_amdgcn_rcpf(x); }
__device__ __forceinline__ float silu_f(float x) { return x * fast_rcp(1.0f + __expf(-x)); }
__device__ __forceinline__ ushort_t f2b(float f) {
    __hip_bfloat16 h = __float2bfloat16(f);
    return __builtin_bit_cast(ushort_t, h);
}
__device__ __forceinline__ uint_t pk2(float a, float b) {
    return (uint_t)f2b(a) | ((uint_t)f2b(b) << 16);
}
// h1-unit permutation: MFMA-row m holds original unit permS(m)
__device__ __forceinline__ int permS(int m) {
    return ((m >> 2) & 3) * 8 + (m & 3) + ((m >> 4) & 1) * 4 + ((m >> 5) & 1) * 32;
}

struct AArgs { const float *aW1, *ab1, *aW2, *ab2, *b3, *scale, *res; };
struct PArgs { const float *W1, *b1, *W2, *b2, *W3; };

// ================= fused sel gate + geometry =================
__global__ __launch_bounds__(64) void selgeom_kernel(
    const float* __restrict__ z,
    const float* __restrict__ W1, const float* __restrict__ b1,
    const float* __restrict__ W2, const float* __restrict__ b2,
    const float* __restrict__ W3, const float* __restrict__ b3,
    float* __restrict__ s_out, float* __restrict__ out)
{
    int b = blockIdx.x;
    int t = threadIdx.x;
    __shared__ float zs[64];
    __shared__ float h1[64];
    __shared__ float h2[32];
    __shared__ float sg;
    zs[t] = z[b * 64 + t];
    __syncthreads();
    {
        float acc = b1[t];
        #pragma unroll
        for (int i = 0; i < 64; ++i) acc += zs[i] * W1[i * 64 + t];
        h1[t] = silu_f(acc);
    }
    __syncthreads();
    if (t < 32) {
        float acc = b2[t];
        #pragma unroll
        for (int i = 0; i < 64; ++i) acc += h1[i] * W2[i * 32 + t];
        h2[t] = silu_f(acc);
    }
    __syncthreads();
    if (t == 0) {
        float acc = b3[0];
        #pragma unroll
        for (int i = 0; i < 32; ++i) acc += h2[i] * W3[i];
        float s = fast_rcp(1.0f + __expf(-acc));
        sg = s;
        s_out[b] = s;
    }
    __syncthreads();
    float s = sg;
    float* row = out + (size_t)b * XCOLS;
    {
        float v = zs[t] * s;
        row[COL_Z + t] = fminf(fmaxf(v, -1e6f), 1e6f);
    }
    #pragma unroll
    for (int rep = 0; rep < 2; ++rep) {
        int p = t + rep * 64;
        if (p < NPAIRS) {
            int i = 0, pp = p;
            while (pp >= 15 - i) { pp -= 15 - i; ++i; }
            int j = i + 1 + pp;
            float dx = zs[i * 4 + 0] - zs[j * 4 + 0];
            float dy = zs[i * 4 + 1] - zs[j * 4 + 1];
            float d = sqrtf(dx * dx + dy * dy);
            d = fmaxf(d, 0.001f);
            float inv_d = fast_rcp(d + 0.1f);
            float inv_sq = fast_rcp(d * d + 0.1f);
            float exp_d = __expf(-fminf(d, 20.0f));
            float screened = exp_d * inv_d;
            float log_d = __logf(d + 1.0f);
            row[COL_D + p] = d * s;
            row[COL_INVD + p] = inv_d * s;
            row[COL_INVSQ + p] = inv_sq * s;
            row[COL_EXPD + p] = exp_d * s;
            row[COL_SCR + p] = screened * s;
            row[COL_LOGD + p] = log_d * s;
        }
    }
}

// ================= xprep: per-row x-frags + attention + tail; blocks>=1096 do weight prep =================
__global__ __launch_bounds__(256) void xprep_kernel(
    const float* __restrict__ z,
    AArgs apw, AArgs anda, AArgs agl,
    PArgs ppw, PArgs pnd, PArgs pgl,
    char* __restrict__ ws)
{
    const int bid = blockIdx.x;
    if (bid >= 1096) {
        // ---------- weight prep (grid-stride over 128 blocks) ----------
        int t0 = (bid - 1096) * 256 + threadIdx.x;
        const int STR = 128 * 256;
        if (t0 < 64) ((float*)(ws + WS_ZERO))[t0] = 0.f;
        for (int t = t0; t < 8192; t += STR) {
            int u = t & 4095;
            int n = u >> 9, m = (u >> 3) & 63, k = u & 7;
            int sm = permS(m);
            if (t < 4096)
                ((ushort_t*)(ws + WS_W1T_PW))[u] = f2b(ppw.W1[n * 512 + k * 64 + sm]);
            else
                ((ushort_t*)(ws + WS_W1T_ND))[u] =
                    (k < 4) ? f2b(pnd.W1[n * 256 + k * 64 + sm]) : (ushort_t)0;
        }
        for (int t = t0; t < 32768; t += STR) {
            int n = t >> 12, m = (t >> 6) & 63, k = t & 63;
            ((ushort_t*)(ws + WS_W1T_GL))[t] = f2b(pgl.W1[n * 4096 + k * 64 + permS(m)]);
        }
        for (int t = t0; t < 3 * 32768; t += STR) {
            int which = t >> 15, u = t & 32767;
            int n = u >> 12, kb = (u >> 9) & 7, col = (u >> 3) & 63, e = u & 7;
            int k = (kb & 3) * 8 + e + ((kb >> 2) << 5);
            const float* src = which == 0 ? ppw.W2 : which == 1 ? pnd.W2 : pgl.W2;
            ushort_t* dst = (ushort_t*)(ws + (which == 0 ? WS_W2T_PW : which == 1 ? WS_W2T_ND : WS_W2T_GL));
            dst[u] = f2b(src[n * 4096 + k * 64 + col]);
        }
        for (int t = t0; t < 1536; t += STR) {
            int which = t >> 9, u = t & 511;
            int n = u >> 6, m = u & 63;
            const float* b1 = which == 0 ? ppw.b1 : which == 1 ? pnd.b1 : pgl.b1;
            float* dst = (float*)(ws + (which == 0 ? WS_B1D_PW : which == 1 ? WS_B1D_ND : WS_B1D_GL));
            dst[u] = b1[n * 64 + permS(m)];
        }
        for (int t = t0; t < 1536; t += STR) {
            int which = t >> 9, u = t & 511;
            const float* b2 = which == 0 ? ppw.b2 : which == 1 ? pnd.b2 : pgl.b2;
            const float* W3 = which == 0 ? ppw.W3 : which == 1 ? pnd.W3 : pgl.W3;
            float2* dst = (float2*)(ws + (which == 0 ? WS_BW3_PW : which == 1 ? WS_BW3_ND : WS_BW3_GL));
            dst[u] = make_float2(b2[u], W3[u]);
        }
        return;
    }

    // ---------- per-row prep (blocks are segment-uniform: 960 pw, 128 nd, 8 gl) ----------
    const int urow = bid * 256 + threadIdx.x;   // 1096*256 == RTOT exactly
    const float* sg = (const float*)(ws + WS_SGATE);
    float a1acc[32];
    float mean, s;
    AArgs A;

    if (urow < RPW) {
        A = apw;
        int b = urow / 120, p = urow - b * 120;
        int i = 0, pp = p;
        while (pp >= 15 - i) { pp -= 15 - i; ++i; }
        int j = i + 1 + pp;
        const float* zb = z + b * 64;
        float4 xa = *(const float4*)(zb + i * 4);
        float4 xb = *(const float4*)(zb + j * 4);
        float x[8] = {xa.x, xa.y, xa.z, xa.w, xb.x, xb.y, xb.z, xb.w};
        uint4 xw = make_uint4(pk2(x[0], x[1]), pk2(x[2], x[3]), pk2(x[4], x[5]), pk2(x[6], x[7]));
        *(uint4*)(ws + WS_XF + (size_t)urow * 16) = xw;
        mean = (x[0] + x[1] + x[2] + x[3] + x[4] + x[5] + x[6] + x[7]) * 0.125f;
        #pragma unroll
        for (int u = 0; u < 32; ++u) {
            float acc = A.ab1[u];
            #pragma unroll
            for (int q = 0; q < 8; ++q) acc += x[q] * A.aW1[q * 32 + u];
            a1acc[u] = acc;
        }
        s = sg[b];
    } else if (urow < RPW + RND) {
        A = anda;
        int loc = urow - RPW;
        int b = loc >> 4, node = loc & 15;
        float4 xa = *(const float4*)(z + b * 64 + node * 4);
        float x[4] = {xa.x, xa.y, xa.z, xa.w};
        uint4 xw = make_uint4(pk2(x[0], x[1]), pk2(x[2], x[3]), 0u, 0u);
        *(uint4*)(ws + WS_XF + (size_t)urow * 16) = xw;
        mean = (x[0] + x[1] + x[2] + x[3]) * 0.25f;
        #pragma unroll
        for (int u = 0; u < 32; ++u) {
            float acc = A.ab1[u];
            #pragma unroll
            for (int q = 0; q < 4; ++q) acc += x[q] * A.aW1[q * 32 + u];
            a1acc[u] = acc;
        }
        s = sg[b];
    } else {
        A = agl;
        int r = urow - (RPW + RND);
        const float* zr = z + (size_t)r * 64;
        #pragma unroll
        for (int u = 0; u < 32; ++u) a1acc[u] = A.ab1[u];
        float mn = 0.f;
        #pragma unroll
        for (int c = 0; c < 8; ++c) {
            float4 f0 = *(const float4*)(zr + c * 8);
            float4 f1 = *(const float4*)(zr + c * 8 + 4);
            float xs[8] = {f0.x, f0.y, f0.z, f0.w, f1.x, f1.y, f1.z, f1.w};
            uint4 xw = make_uint4(pk2(xs[0], xs[1]), pk2(xs[2], xs[3]),
                                  pk2(xs[4], xs[5]), pk2(xs[6], xs[7]));
            *(uint4*)(ws + WS_XGL + (size_t)r * 128 + c * 16) = xw;
            #pragma unroll
            for (int q = 0; q < 8; ++q) {
                mn += xs[q];
                float xk = xs[q];
                #pragma unroll
                for (int u = 0; u < 32; ++u) a1acc[u] += xk * A.aW1[(c * 8 + q) * 32 + u];
            }
        }
        mean = mn * (1.0f / 64.0f);
        s = sg[r];
    }

    // attention finish + softmax + fold scale & gate
    float lg[8];
    #pragma unroll
    for (int n = 0; n < 8; ++n) lg[n] = A.ab2[n];
    #pragma unroll
    for (int u = 0; u < 32; ++u) {
        float a1 = silu_f(a1acc[u]);
        #pragma unroll
        for (int n = 0; n < 8; ++n) lg[n] += a1 * A.aW2[u * 8 + n];
    }
    float m = lg[0];
    #pragma unroll
    for (int n = 1; n < 8; ++n) m = fmaxf(m, lg[n]);
    float sum = 0.f;
    #pragma unroll
    for (int n = 0; n < 8; ++n) { lg[n] = __expf(lg[n] - m); sum += lg[n]; }
    float inv = fast_rcp(sum);
    float tail = 0.f;
    float as_[8];
    #pragma unroll
    for (int n = 0; n < 8; ++n) {
        float a_n = lg[n] * inv * A.scale[n];
        tail += a_n * A.b3[n];
        as_[n] = a_n * s;
    }
    float* ag = (float*)(ws + WS_ATT) + (size_t)urow * 8;
    *(float4*)(ag + 0) = make_float4(as_[0], as_[1], as_[2], as_[3]);
    *(float4*)(ag + 4) = make_float4(as_[4], as_[5], as_[6], as_[7]);
    ((float*)(ws + WS_TAIL))[urow] = (tail + A.res[0] * mean) * s;
}

// ================= main basis kernel: gl[0..31] + pw[32..3871] + nd[3872..4383] =================
#define H2_EPILOGUE \
  { \
    const float* bp = b1base + n * 64 + g * 4; \
    float4 bb0 = *(const float4*)(bp); \
    float4 bb1 = *(const float4*)(bp + 16); \
    float4 bb2 = *(const float4*)(bp + 32); \
    float4 bb3 = *(const float4*)(bp + 48); \
    union { bf16x8 v; uint_t u[4]; } A0, A1; \
    A0.u[0] = pk2(silu_f(d0[0] + bb0.x), silu_f(d0[1] + bb0.y)); \
    A0.u[1] = pk2(silu_f(d0[2] + bb0.z), silu_f(d0[3] + bb0.w)); \
    A0.u[2] = pk2(silu_f(d1[0] + bb1.x), silu_f(d1[1] + bb1.y)); \
    A0.u[3] = pk2(silu_f(d1[2] + bb1.z), silu_f(d1[3] + bb1.w)); \
    A1.u[0] = pk2(silu_f(d2[0] + bb2.x), silu_f(d2[1] + bb2.y)); \
    A1.u[1] = pk2(silu_f(d2[2] + bb2.z), silu_f(d2[3] + bb2.w)); \
    A1.u[2] = pk2(silu_f(d3[0] + bb3.x), silu_f(d3[1] + bb3.y)); \
    A1.u[3] = pk2(silu_f(d3[2] + bb3.z), silu_f(d3[3] + bb3.w)); \
    const char* w2p = ws + (w2l + (uint_t)n * 8192u); \
    float pv0 = 0.f, pv1 = 0.f, pv2 = 0.f, pv3 = 0.f; \
    _Pragma("unroll") \
    for (int cb = 0; cb < 4; ++cb) { \
      bf16x8 bf0 = *(const bf16x8*)(w2p + cb * 256); \
      bf16x8 bf1 = *(const bf16x8*)(w2p + cb * 256 + 4096); \
      f32x4 acc = {0.f, 0.f, 0.f, 0.f}; \
      acc = __builtin_amdgcn_mfma_f32_16x16x32_bf16(A0.v, bf0, acc, 0, 0, 0); \
      acc = __builtin_amdgcn_mfma_f32_16x16x32_bf16(A1.v, bf1, acc, 0, 0, 0); \
      float2 bw = bwbase[n * 64 + cb * 16 + lo]; \
      pv0 += silu_f(acc[0] + bw.x) * bw.y; \
      pv1 += silu_f(acc[1] + bw.x) * bw.y; \
      pv2 += silu_f(acc[2] + bw.x) * bw.y; \
      pv3 += silu_f(acc[3] + bw.x) * bw.y; \
    } \
    oa0 += Att[attb + 0 * 9 + n] * pv0; \
    oa1 += Att[attb + 1 * 9 + n] * pv1; \
    oa2 += Att[attb + 2 * 9 + n] * pv2; \
    oa3 += Att[attb + 3 * 9 + n] * pv3; \
  }

__global__ __launch_bounds__(256, 4) void basis_main_kernel(
    const char* __restrict__ ws, float* __restrict__ out)
{
    __shared__ float Att[64 * 9];   // [row][0..7]=att*scale*s, [8]=tail'
    const int tid = threadIdx.x;
    const int lane = tid & 63;
    const int wave = tid >> 6;
    const int g = lane >> 4;
    const int lo = lane & 15;

    const int bid = blockIdx.x;
    int fam, rowbase, ubase;
    uint_t w1t_off, w2t_off, b1d_off, bw3_off;
    if (bid < GL_BLK) {
        fam = 2; rowbase = bid * 64; ubase = RPW + RND + rowbase;
        w1t_off = WS_W1T_GL; w2t_off = WS_W2T_GL; b1d_off = WS_B1D_GL; bw3_off = WS_BW3_GL;
    } else if (bid < GL_BLK + PW_BLK) {
        fam = 0; rowbase = (bid - GL_BLK) * 64; ubase = rowbase;
        w1t_off = WS_W1T_PW; w2t_off = WS_W2T_PW; b1d_off = WS_B1D_PW; bw3_off = WS_BW3_PW;
    } else {
        fam = 1; rowbase = (bid - (GL_BLK + PW_BLK)) * 64; ubase = RPW + rowbase;
        w1t_off = WS_W1T_ND; w2t_off = WS_W2T_ND; b1d_off = WS_B1D_ND; bw3_off = WS_BW3_ND;
    }

    // stage att' + tail' to LDS (coalesced)
    {
        const float* ag = (const float*)(ws + WS_ATT) + (size_t)ubase * 8;
        #pragma unroll
        for (int q = 0; q < 2; ++q) {
            int idx = tid + q * 256;
            Att[(idx >> 3) * 9 + (idx & 7)] = ag[idx];
        }
        if (tid < 64) Att[tid * 9 + 8] = ((const float*)(ws + WS_TAIL))[ubase + tid];
    }

    // B-operand fragments (basis-invariant)
    bf16x8 xf0, xf1;
    if (fam == 2) {
        const char* xg = ws + WS_XGL + (size_t)(rowbase + wave * 16 + lo) * 128;
        xf0 = *(const bf16x8*)(xg + g * 16);
        xf1 = *(const bf16x8*)(xg + 64 + g * 16);
    } else {
        uint_t xoff = (g == 0) ? (WS_XF + (uint_t)(ubase + wave * 16 + lo) * 16u) : WS_ZERO;
        xf0 = *(const bf16x8*)(ws + xoff);
    }
    __syncthreads();

    const float* b1base = (const float*)(ws + b1d_off);
    const float2* bwbase = (const float2*)(ws + bw3_off);
    const int attb = (wave * 16 + g * 4) * 9;
    const uint_t w2l = w2t_off + (uint_t)(g * 1024 + lo * 16);

    float oa0 = 0.f, oa1 = 0.f, oa2 = 0.f, oa3 = 0.f;
    const f32x4 zr4 = {0.f, 0.f, 0.f, 0.f};

    if (fam != 2) {
        const uint_t abase = w1t_off + (uint_t)(lo * 16);
        for (int n = 0; n < 8; ++n) {
            uint_t an = abase + (uint_t)n * 1024u;
            bf16x8 af0 = *(const bf16x8*)(ws + ((g == 0) ? an : WS_ZERO));
            bf16x8 af1 = *(const bf16x8*)(ws + ((g == 0) ? an + 256u : WS_ZERO));
            bf16x8 af2 = *(const bf16x8*)(ws + ((g == 0) ? an + 512u : WS_ZERO));
            bf16x8 af3 = *(const bf16x8*)(ws + ((g == 0) ? an + 768u : WS_ZERO));
            f32x4 d0 = __builtin_amdgcn_mfma_f32_16x16x32_bf16(af0, xf0, zr4, 0, 0, 0);
            f32x4 d1 = __builtin_amdgcn_mfma_f32_16x16x32_bf16(af1, xf0, zr4, 0, 0, 0);
            f32x4 d2 = __builtin_amdgcn_mfma_f32_16x16x32_bf16(af2, xf0, zr4, 0, 0, 0);
            f32x4 d3 = __builtin_amdgcn_mfma_f32_16x16x32_bf16(af3, xf0, zr4, 0, 0, 0);
            H2_EPILOGUE
        }
    } else {
        const uint_t abase = w1t_off + (uint_t)(lo * 128 + g * 16);
        for (int n = 0; n < 8; ++n) {
            const char* w1n = ws + (abase + (uint_t)n * 8192u);
            f32x4 d0 = __builtin_amdgcn_mfma_f32_16x16x32_bf16(*(const bf16x8*)(w1n +    0), xf0, zr4, 0, 0, 0);
            d0 = __builtin_amdgcn_mfma_f32_16x16x32_bf16(*(const bf16x8*)(w1n +   64), xf1, d0, 0, 0, 0);
            f32x4 d1 = __builtin_amdgcn_mfma_f32_16x16x32_bf16(*(const bf16x8*)(w1n + 2048), xf0, zr4, 0, 0, 0);
            d1 = __builtin_amdgcn_mfma_f32_16x16x32_bf16(*(const bf16x8*)(w1n + 2112), xf1, d1, 0, 0, 0);
            f32x4 d2 = __builtin_amdgcn_mfma_f32_16x16x32_bf16(*(const bf16x8*)(w1n + 4096), xf0, zr4, 0, 0, 0);
            d2 = __builtin_amdgcn_mfma_f32_16x16x32_bf16(*(const bf16x8*)(w1n + 4160), xf1, d2, 0, 0, 0);
            f32x4 d3 = __builtin_amdgcn_mfma_f32_16x16x32_bf16(*(const bf16x8*)(w1n + 6144), xf0, zr4, 0, 0, 0);
            d3 = __builtin_amdgcn_mfma_f32_16x16x32_bf16(*(const bf16x8*)(w1n + 6208), xf1, d3, 0, 0, 0);
            H2_EPILOGUE
        }
    }

    // reduce over the 16 h2-column lanes, store
    float ov[4] = {oa0, oa1, oa2, oa3};
    #pragma unroll
    for (int r = 0; r < 4; ++r) {
        float v = ov[r];
        v += __shfl_xor(v, 1);
        v += __shfl_xor(v, 2);
        v += __shfl_xor(v, 4);
        v += __shfl_xor(v, 8);
        if (lo == 0) {
            int row_l = wave * 16 + g * 4 + r;
            int rg = rowbase + row_l;
            int bb, colo;
            if (fam == 0) { bb = rg / 120; colo = COL_PW + (rg - bb * 120); }
            else if (fam == 1) { bb = rg >> 4; colo = COL_ND + (rg & 15); }
            else { bb = rg; colo = COL_GL; }
            float o = v + Att[row_l * 9 + 8];
            o = fminf(fmaxf(o, -1e6f), 1e6f);
            out[(size_t)bb * XCOLS + colo] = o;
        }
    }
}

extern "C" void kernel_launch(void* const* d_in, const int* in_sizes, int n_in,
                              void* d_out, int out_size, void* d_ws, size_t ws_size,
                              hipStream_t stream) {
    const float* z = (const float*)d_in[0];
    const float* pw[12]; const float* nd[12]; const float* gl[12];
    for (int i = 0; i < 12; ++i) pw[i] = (const float*)d_in[1 + i];
    for (int i = 0; i < 12; ++i) nd[i] = (const float*)d_in[13 + i];
    for (int i = 0; i < 12; ++i) gl[i] = (const float*)d_in[25 + i];
    const float* sel_W1 = (const float*)d_in[37];
    const float* sel_b1 = (const float*)d_in[38];
    const float* sel_W2 = (const float*)d_in[39];
    const float* sel_b2 = (const float*)d_in[40];
    const float* sel_W3 = (const float*)d_in[41];
    const float* sel_b3 = (const float*)d_in[42];

    float* out = (float*)d_out;
    char* ws = (char*)d_ws;

    selgeom_kernel<<<BATCH, 64, 0, stream>>>(
        z, sel_W1, sel_b1, sel_W2, sel_b2, sel_W3, sel_b3,
        (float*)(ws + WS_SGATE), out);

    // param index order: W1,b1,W2,b2,W3,b3,scale,aW1,ab1,aW2,ab2,res
    AArgs apw = {pw[7], pw[8], pw[9], pw[10], pw[5], pw[6], pw[11]};
    AArgs anda = {nd[7], nd[8], nd[9], nd[10], nd[5], nd[6], nd[11]};
    AArgs agl = {gl[7], gl[8], gl[9], gl[10], gl[5], gl[6], gl[11]};
    PArgs ppw = {pw[0], pw[1], pw[2], pw[3], pw[4]};
    PArgs pnd = {nd[0], nd[1], nd[2], nd[3], nd[4]};
    PArgs pgl = {gl[0], gl[1], gl[2], gl[3], gl[4]};

    xprep_kernel<<<1096 + 128, 256, 0, stream>>>(z, apw, anda, agl, ppw, pnd, pgl, ws);

    basis_main_kernel<<<GL_BLK + PW_BLK + ND_BLK, 256, 0, stream>>>(ws, out);
}

// Round 6
// 128.009 us; speedup vs baseline: 20.8099x; 1.0714x over previous
//
#include <hip/hip_runtime.h>
#include <hip/hip_bf16.h>
#include <math.h>

#define XCOLS 921
#define COL_Z 0
#define COL_D 64
#define COL_INVD 184
#define COL_INVSQ 304
#define COL_EXPD 424
#define COL_SCR 544
#define COL_LOGD 664
#define COL_PW 784
#define COL_ND 904
#define COL_GL 920

#define BATCH 2048
#define NPAIRS 120
#define RPW (BATCH * NPAIRS)       /* 245760 */
#define RND (BATCH * 16)           /* 32768  */
#define RGL BATCH                  /* 2048   */
#define RTOT (RPW + RND + RGL)     /* 280576 */

#define ROWS_BLK 128
#define TILES 8
#define GL_BLK 16                  /* 2048/128  */
#define PW_BLK 1920                /* 245760/128 */
#define ND_BLK 256                 /* 32768/128 */

// ---- d_ws byte offsets (total ~15.1 MB) ----
#define WS_SGATE   0u
#define WS_ZERO    8192u
#define WS_ONE     8448u
#define WS_BW3_PW  8704u
#define WS_BW3_ND  12800u
#define WS_BW3_GL  16896u
#define WS_B1D_GL  20992u
#define WS_W1T_PW  23040u          /* [8][64][16] bf16: k<8 W1, k==8 b1 */
#define WS_W1T_ND  39424u
#define WS_W1T_GL  55808u          /* [8][64][64] bf16 */
#define WS_W2T_PW  121344u         /* [8][8kb][64col][8e] bf16 */
#define WS_W2T_ND  186880u
#define WS_W2T_GL  252416u
#define WS_XF      317952u         /* (RPW+RND) x 16B bf16x8 */
#define WS_XGL     4774400u        /* RGL x 128B */
#define WS_ATT     5036544u        /* RTOT x 32B f32x8 (att*scale*gate) */
#define WS_TAIL    14014976u       /* RTOT x 4B */

typedef unsigned short ushort_t;
typedef unsigned int uint_t;
typedef __attribute__((ext_vector_type(8))) short bf16x8;
typedef __attribute__((ext_vector_type(4))) float f32x4;

__device__ __forceinline__ float fast_rcp(float x) { return __builtin_amdgcn_rcpf(x); }
__device__ __forceinline__ float silu_f(float x) { return x * fast_rcp(1.0f + __expf(-x)); }
__device__ __forceinline__ ushort_t f2b(float f) {
    __hip_bfloat16 h = __float2bfloat16(f);
    return __builtin_bit_cast(ushort_t, h);
}
__device__ __forceinline__ uint_t pk2(float a, float b) {
    return (uint_t)f2b(a) | ((uint_t)f2b(b) << 16);
}
// h1-unit permutation: MFMA-row m holds original unit permS(m)
__device__ __forceinline__ int permS(int m) {
    return ((m >> 2) & 3) * 8 + (m & 3) + ((m >> 4) & 1) * 4 + ((m >> 5) & 1) * 32;
}

struct AArgs { const float *aW1, *ab1, *aW2, *ab2, *b3, *scale, *res; };
struct PArgs { const float *W1, *b1, *W2, *b2, *W3; };

// ================= fused sel gate + geometry =================
__global__ __launch_bounds__(64) void selgeom_kernel(
    const float* __restrict__ z,
    const float* __restrict__ W1, const float* __restrict__ b1,
    const float* __restrict__ W2, const float* __restrict__ b2,
    const float* __restrict__ W3, const float* __restrict__ b3,
    float* __restrict__ s_out, float* __restrict__ out)
{
    int b = blockIdx.x;
    int t = threadIdx.x;
    __shared__ float zs[64];
    __shared__ float h1[64];
    __shared__ float h2[32];
    __shared__ float sg;
    zs[t] = z[b * 64 + t];
    __syncthreads();
    {
        float acc = b1[t];
        #pragma unroll
        for (int i = 0; i < 64; ++i) acc += zs[i] * W1[i * 64 + t];
        h1[t] = silu_f(acc);
    }
    __syncthreads();
    if (t < 32) {
        float acc = b2[t];
        #pragma unroll
        for (int i = 0; i < 64; ++i) acc += h1[i] * W2[i * 32 + t];
        h2[t] = silu_f(acc);
    }
    __syncthreads();
    if (t == 0) {
        float acc = b3[0];
        #pragma unroll
        for (int i = 0; i < 32; ++i) acc += h2[i] * W3[i];
        float s = fast_rcp(1.0f + __expf(-acc));
        sg = s;
        s_out[b] = s;
    }
    __syncthreads();
    float s = sg;
    float* row = out + (size_t)b * XCOLS;
    {
        float v = zs[t] * s;
        row[COL_Z + t] = fminf(fmaxf(v, -1e6f), 1e6f);
    }
    #pragma unroll
    for (int rep = 0; rep < 2; ++rep) {
        int p = t + rep * 64;
        if (p < NPAIRS) {
            int i = 0, pp = p;
            while (pp >= 15 - i) { pp -= 15 - i; ++i; }
            int j = i + 1 + pp;
            float dx = zs[i * 4 + 0] - zs[j * 4 + 0];
            float dy = zs[i * 4 + 1] - zs[j * 4 + 1];
            float d = sqrtf(dx * dx + dy * dy);
            d = fmaxf(d, 0.001f);
            float inv_d = fast_rcp(d + 0.1f);
            float inv_sq = fast_rcp(d * d + 0.1f);
            float exp_d = __expf(-fminf(d, 20.0f));
            float screened = exp_d * inv_d;
            float log_d = __logf(d + 1.0f);
            row[COL_D + p] = d * s;
            row[COL_INVD + p] = inv_d * s;
            row[COL_INVSQ + p] = inv_sq * s;
            row[COL_EXPD + p] = exp_d * s;
            row[COL_SCR + p] = screened * s;
            row[COL_LOGD + p] = log_d * s;
        }
    }
}

// ================= xprep: per-row x-frags + attention + tail; blocks>=1096 do weight prep =================
__global__ __launch_bounds__(256) void xprep_kernel(
    const float* __restrict__ z,
    AArgs apw, AArgs anda, AArgs agl,
    PArgs ppw, PArgs pnd, PArgs pgl,
    char* __restrict__ ws)
{
    const int bid = blockIdx.x;
    if (bid >= 1096) {
        // ---------- weight prep (grid-stride over 128 blocks) ----------
        int t0 = (bid - 1096) * 256 + threadIdx.x;
        const int STR = 128 * 256;
        if (t0 < 64) ((float*)(ws + WS_ZERO))[t0] = 0.f;
        if (t0 < 8) ((ushort_t*)(ws + WS_ONE))[t0] = (t0 == 0) ? f2b(1.0f) : (ushort_t)0;
        // W1T16 pw+nd: [8][64][16], k<DIN = W1, k==8 = b1, else 0
        for (int t = t0; t < 16384; t += STR) {
            int which = t >> 13, u = t & 8191;
            int nn = u >> 10, m = (u >> 4) & 63, k = u & 15;
            int sm = permS(m);
            float v;
            if (which == 0)
                v = (k < 8) ? ppw.W1[nn * 512 + k * 64 + sm]
                  : (k == 8 ? ppw.b1[nn * 64 + sm] : 0.f);
            else
                v = (k < 4) ? pnd.W1[nn * 256 + k * 64 + sm]
                  : (k == 8 ? pnd.b1[nn * 64 + sm] : 0.f);
            ((ushort_t*)(ws + (which == 0 ? WS_W1T_PW : WS_W1T_ND)))[u] = f2b(v);
        }
        // gl W1T [8][64][64] + permuted b1
        for (int t = t0; t < 32768; t += STR) {
            int nn = t >> 12, m = (t >> 6) & 63, k = t & 63;
            ((ushort_t*)(ws + WS_W1T_GL))[t] = f2b(pgl.W1[nn * 4096 + k * 64 + permS(m)]);
        }
        for (int t = t0; t < 512; t += STR) {
            int nn = t >> 6, m = t & 63;
            ((float*)(ws + WS_B1D_GL))[t] = pgl.b1[nn * 64 + permS(m)];
        }
        // W2T x3
        for (int t = t0; t < 3 * 32768; t += STR) {
            int which = t >> 15, u = t & 32767;
            int nn = u >> 12, kb = (u >> 9) & 7, col = (u >> 3) & 63, e = u & 7;
            int k = (kb & 3) * 8 + e + ((kb >> 2) << 5);
            const float* src = which == 0 ? ppw.W2 : which == 1 ? pnd.W2 : pgl.W2;
            ushort_t* dst = (ushort_t*)(ws + (which == 0 ? WS_W2T_PW : which == 1 ? WS_W2T_ND : WS_W2T_GL));
            dst[u] = f2b(src[nn * 4096 + k * 64 + col]);
        }
        // packed {b2, W3} x3
        for (int t = t0; t < 1536; t += STR) {
            int which = t >> 9, u = t & 511;
            const float* b2 = which == 0 ? ppw.b2 : which == 1 ? pnd.b2 : pgl.b2;
            const float* W3 = which == 0 ? ppw.W3 : which == 1 ? pnd.W3 : pgl.W3;
            float2* dst = (float2*)(ws + (which == 0 ? WS_BW3_PW : which == 1 ? WS_BW3_ND : WS_BW3_GL));
            dst[u] = make_float2(b2[u], W3[u]);
        }
        return;
    }

    // ---------- per-row prep (blocks segment-uniform: 960 pw, 128 nd, 8 gl) ----------
    const int urow = bid * 256 + threadIdx.x;   // 1096*256 == RTOT exactly
    const float* sg = (const float*)(ws + WS_SGATE);
    float a1acc[32];
    float mean, s;
    AArgs A;

    if (urow < RPW) {
        A = apw;
        int b = urow / 120, p = urow - b * 120;
        int i = 0, pp = p;
        while (pp >= 15 - i) { pp -= 15 - i; ++i; }
        int j = i + 1 + pp;
        const float* zb = z + b * 64;
        float4 xa = *(const float4*)(zb + i * 4);
        float4 xb = *(const float4*)(zb + j * 4);
        float x[8] = {xa.x, xa.y, xa.z, xa.w, xb.x, xb.y, xb.z, xb.w};
        uint4 xw = make_uint4(pk2(x[0], x[1]), pk2(x[2], x[3]), pk2(x[4], x[5]), pk2(x[6], x[7]));
        *(uint4*)(ws + WS_XF + (size_t)urow * 16) = xw;
        mean = (x[0] + x[1] + x[2] + x[3] + x[4] + x[5] + x[6] + x[7]) * 0.125f;
        #pragma unroll
        for (int u = 0; u < 32; ++u) {
            float acc = A.ab1[u];
            #pragma unroll
            for (int q = 0; q < 8; ++q) acc += x[q] * A.aW1[q * 32 + u];
            a1acc[u] = acc;
        }
        s = sg[b];
    } else if (urow < RPW + RND) {
        A = anda;
        int loc = urow - RPW;
        int b = loc >> 4, node = loc & 15;
        float4 xa = *(const float4*)(z + b * 64 + node * 4);
        float x[4] = {xa.x, xa.y, xa.z, xa.w};
        uint4 xw = make_uint4(pk2(x[0], x[1]), pk2(x[2], x[3]), 0u, 0u);
        *(uint4*)(ws + WS_XF + (size_t)urow * 16) = xw;
        mean = (x[0] + x[1] + x[2] + x[3]) * 0.25f;
        #pragma unroll
        for (int u = 0; u < 32; ++u) {
            float acc = A.ab1[u];
            #pragma unroll
            for (int q = 0; q < 4; ++q) acc += x[q] * A.aW1[q * 32 + u];
            a1acc[u] = acc;
        }
        s = sg[b];
    } else {
        A = agl;
        int r = urow - (RPW + RND);
        const float* zr = z + (size_t)r * 64;
        #pragma unroll
        for (int u = 0; u < 32; ++u) a1acc[u] = A.ab1[u];
        float mn = 0.f;
        #pragma unroll
        for (int c = 0; c < 8; ++c) {
            float4 f0 = *(const float4*)(zr + c * 8);
            float4 f1 = *(const float4*)(zr + c * 8 + 4);
            float xs[8] = {f0.x, f0.y, f0.z, f0.w, f1.x, f1.y, f1.z, f1.w};
            uint4 xw = make_uint4(pk2(xs[0], xs[1]), pk2(xs[2], xs[3]),
                                  pk2(xs[4], xs[5]), pk2(xs[6], xs[7]));
            *(uint4*)(ws + WS_XGL + (size_t)r * 128 + c * 16) = xw;
            #pragma unroll
            for (int q = 0; q < 8; ++q) {
                mn += xs[q];
                float xk = xs[q];
                #pragma unroll
                for (int u = 0; u < 32; ++u) a1acc[u] += xk * A.aW1[(c * 8 + q) * 32 + u];
            }
        }
        mean = mn * (1.0f / 64.0f);
        s = sg[r];
    }

    float lg[8];
    #pragma unroll
    for (int n = 0; n < 8; ++n) lg[n] = A.ab2[n];
    #pragma unroll
    for (int u = 0; u < 32; ++u) {
        float a1 = silu_f(a1acc[u]);
        #pragma unroll
        for (int n = 0; n < 8; ++n) lg[n] += a1 * A.aW2[u * 8 + n];
    }
    float m = lg[0];
    #pragma unroll
    for (int n = 1; n < 8; ++n) m = fmaxf(m, lg[n]);
    float sum = 0.f;
    #pragma unroll
    for (int n = 0; n < 8; ++n) { lg[n] = __expf(lg[n] - m); sum += lg[n]; }
    float inv = fast_rcp(sum);
    float tail = 0.f;
    float as_[8];
    #pragma unroll
    for (int n = 0; n < 8; ++n) {
        float a_n = lg[n] * inv * A.scale[n];
        tail += a_n * A.b3[n];
        as_[n] = a_n * s;
    }
    float* ag = (float*)(ws + WS_ATT) + (size_t)urow * 8;
    *(float4*)(ag + 0) = make_float4(as_[0], as_[1], as_[2], as_[3]);
    *(float4*)(ag + 4) = make_float4(as_[4], as_[5], as_[6], as_[7]);
    ((float*)(ws + WS_TAIL))[urow] = (tail + A.res[0] * mean) * s;
}

// ================= main basis kernel: 512 thr = 8 waves = 8 bases; 128 rows/block =================
// grid: gl [0,16) | pw [16,1936) | nd [1936,2192)
__global__ __launch_bounds__(512, 4) void basis_main_kernel(
    const char* __restrict__ ws, float* __restrict__ out)
{
    __shared__ float Att[ROWS_BLK * 9];   // [row][0..7]=att', [8]=tail'
    __shared__ float Part[8][ROWS_BLK];
    const int tid = threadIdx.x;
    const int lane = tid & 63;
    const int n = tid >> 6;               // wave index == basis index
    const int g = lane >> 4;
    const int lo = lane & 15;

    const int bid = blockIdx.x;
    int fam, rowbase, ubase;
    uint_t w1t_off, w2t_off, bw3_off;
    if (bid < GL_BLK) {
        fam = 2; rowbase = bid * ROWS_BLK; ubase = RPW + RND + rowbase;
        w1t_off = WS_W1T_GL; w2t_off = WS_W2T_GL; bw3_off = WS_BW3_GL;
    } else if (bid < GL_BLK + PW_BLK) {
        fam = 0; rowbase = (bid - GL_BLK) * ROWS_BLK; ubase = rowbase;
        w1t_off = WS_W1T_PW; w2t_off = WS_W2T_PW; bw3_off = WS_BW3_PW;
    } else {
        fam = 1; rowbase = (bid - (GL_BLK + PW_BLK)) * ROWS_BLK; ubase = RPW + rowbase;
        w1t_off = WS_W1T_ND; w2t_off = WS_W2T_ND; bw3_off = WS_BW3_ND;
    }

    // stage att' + tail' to LDS (coalesced)
    {
        const float* ag = (const float*)(ws + WS_ATT) + (size_t)ubase * 8;
        #pragma unroll
        for (int q = 0; q < 2; ++q) {
            int idx = tid + q * 512;
            Att[(idx >> 3) * 9 + (idx & 7)] = ag[idx];
        }
        if (tid < ROWS_BLK) Att[tid * 9 + 8] = ((const float*)(ws + WS_TAIL))[ubase + tid];
    }

    // persistent per-wave weights
    const char* w2base = ws + w2t_off + (uint_t)(n * 8192 + g * 1024 + lo * 16);
    bf16x8 w2f0[4], w2f1[4];
    #pragma unroll
    for (int cb = 0; cb < 4; ++cb) {
        w2f0[cb] = *(const bf16x8*)(w2base + cb * 256);
        w2f1[cb] = *(const bf16x8*)(w2base + cb * 256 + 4096);
    }
    float2 bw[4];
    #pragma unroll
    for (int cb = 0; cb < 4; ++cb)
        bw[cb] = ((const float2*)(ws + bw3_off))[n * 64 + cb * 16 + lo];

    __syncthreads();

    const f32x4 zr4 = {0.f, 0.f, 0.f, 0.f};

    if (fam != 2) {
        // A-frags persistent: [n][m][16] bf16, g==0 -> k0-7 (W1), g==1 -> k8-15 (b1 @ k8)
        bf16x8 af[4];
        #pragma unroll
        for (int mt = 0; mt < 4; ++mt) {
            uint_t a = (g < 2) ? (w1t_off + (uint_t)(n * 2048 + (mt * 16 + lo) * 32 + g * 16))
                               : WS_ZERO;
            af[mt] = *(const bf16x8*)(ws + a);
        }
        #pragma unroll 1
        for (int t = 0; t < TILES; ++t) {
            uint_t xoff = (g == 0) ? (WS_XF + (uint_t)(ubase + t * 16 + lo) * 16u)
                        : (g == 1) ? WS_ONE : WS_ZERO;
            bf16x8 xf = *(const bf16x8*)(ws + xoff);
            f32x4 d0 = __builtin_amdgcn_mfma_f32_16x16x32_bf16(af[0], xf, zr4, 0, 0, 0);
            f32x4 d1 = __builtin_amdgcn_mfma_f32_16x16x32_bf16(af[1], xf, zr4, 0, 0, 0);
            f32x4 d2 = __builtin_amdgcn_mfma_f32_16x16x32_bf16(af[2], xf, zr4, 0, 0, 0);
            f32x4 d3 = __builtin_amdgcn_mfma_f32_16x16x32_bf16(af[3], xf, zr4, 0, 0, 0);
            union { bf16x8 v; uint_t u[4]; } A0, A1;
            A0.u[0] = pk2(silu_f(d0[0]), silu_f(d0[1]));
            A0.u[1] = pk2(silu_f(d0[2]), silu_f(d0[3]));
            A0.u[2] = pk2(silu_f(d1[0]), silu_f(d1[1]));
            A0.u[3] = pk2(silu_f(d1[2]), silu_f(d1[3]));
            A1.u[0] = pk2(silu_f(d2[0]), silu_f(d2[1]));
            A1.u[1] = pk2(silu_f(d2[2]), silu_f(d2[3]));
            A1.u[2] = pk2(silu_f(d3[0]), silu_f(d3[1]));
            A1.u[3] = pk2(silu_f(d3[2]), silu_f(d3[3]));
            float pv0 = 0.f, pv1 = 0.f, pv2 = 0.f, pv3 = 0.f;
            #pragma unroll
            for (int cb = 0; cb < 4; ++cb) {
                f32x4 acc = __builtin_amdgcn_mfma_f32_16x16x32_bf16(A0.v, w2f0[cb], zr4, 0, 0, 0);
                acc = __builtin_amdgcn_mfma_f32_16x16x32_bf16(A1.v, w2f1[cb], acc, 0, 0, 0);
                pv0 += silu_f(acc[0] + bw[cb].x) * bw[cb].y;
                pv1 += silu_f(acc[1] + bw[cb].x) * bw[cb].y;
                pv2 += silu_f(acc[2] + bw[cb].x) * bw[cb].y;
                pv3 += silu_f(acc[3] + bw[cb].x) * bw[cb].y;
            }
            float pvv[4] = {pv0, pv1, pv2, pv3};
            #pragma unroll
            for (int r = 0; r < 4; ++r) {
                float v = pvv[r];
                v += __shfl_xor(v, 1);
                v += __shfl_xor(v, 2);
                v += __shfl_xor(v, 4);
                v += __shfl_xor(v, 8);
                if (lo == 0) {
                    int row = t * 16 + g * 4 + r;
                    Part[n][row] = Att[row * 9 + n] * v;
                }
            }
        }
    } else {
        // gl: A-frags reloaded per tile (keeps kernel-wide VGPR low); explicit b1
        float4 b1r[4];
        #pragma unroll
        for (int mt = 0; mt < 4; ++mt)
            b1r[mt] = *(const float4*)(ws + WS_B1D_GL + (uint_t)(n * 64 + mt * 16 + g * 4) * 4u);
        const char* w1b = ws + w1t_off + (uint_t)(n * 8192 + g * 16 + lo * 128);
        #pragma unroll 1
        for (int t = 0; t < TILES; ++t) {
            const char* xg = ws + WS_XGL + (size_t)(rowbase + t * 16 + lo) * 128;
            bf16x8 xf0 = *(const bf16x8*)(xg + g * 16);
            bf16x8 xf1 = *(const bf16x8*)(xg + 64 + g * 16);
            f32x4 d0 = __builtin_amdgcn_mfma_f32_16x16x32_bf16(*(const bf16x8*)(w1b + 0), xf0, zr4, 0, 0, 0);
            d0 = __builtin_amdgcn_mfma_f32_16x16x32_bf16(*(const bf16x8*)(w1b + 64), xf1, d0, 0, 0, 0);
            f32x4 d1 = __builtin_amdgcn_mfma_f32_16x16x32_bf16(*(const bf16x8*)(w1b + 2048), xf0, zr4, 0, 0, 0);
            d1 = __builtin_amdgcn_mfma_f32_16x16x32_bf16(*(const bf16x8*)(w1b + 2112), xf1, d1, 0, 0, 0);
            f32x4 d2 = __builtin_amdgcn_mfma_f32_16x16x32_bf16(*(const bf16x8*)(w1b + 4096), xf0, zr4, 0, 0, 0);
            d2 = __builtin_amdgcn_mfma_f32_16x16x32_bf16(*(const bf16x8*)(w1b + 4160), xf1, d2, 0, 0, 0);
            f32x4 d3 = __builtin_amdgcn_mfma_f32_16x16x32_bf16(*(const bf16x8*)(w1b + 6144), xf0, zr4, 0, 0, 0);
            d3 = __builtin_amdgcn_mfma_f32_16x16x32_bf16(*(const bf16x8*)(w1b + 6208), xf1, d3, 0, 0, 0);
            union { bf16x8 v; uint_t u[4]; } A0, A1;
            A0.u[0] = pk2(silu_f(d0[0] + b1r[0].x), silu_f(d0[1] + b1r[0].y));
            A0.u[1] = pk2(silu_f(d0[2] + b1r[0].z), silu_f(d0[3] + b1r[0].w));
            A0.u[2] = pk2(silu_f(d1[0] + b1r[1].x), silu_f(d1[1] + b1r[1].y));
            A0.u[3] = pk2(silu_f(d1[2] + b1r[1].z), silu_f(d1[3] + b1r[1].w));
            A1.u[0] = pk2(silu_f(d2[0] + b1r[2].x), silu_f(d2[1] + b1r[2].y));
            A1.u[1] = pk2(silu_f(d2[2] + b1r[2].z), silu_f(d2[3] + b1r[2].w));
            A1.u[2] = pk2(silu_f(d3[0] + b1r[3].x), silu_f(d3[1] + b1r[3].y));
            A1.u[3] = pk2(silu_f(d3[2] + b1r[3].z), silu_f(d3[3] + b1r[3].w));
            float pv0 = 0.f, pv1 = 0.f, pv2 = 0.f, pv3 = 0.f;
            #pragma unroll
            for (int cb = 0; cb < 4; ++cb) {
                f32x4 acc = __builtin_amdgcn_mfma_f32_16x16x32_bf16(A0.v, w2f0[cb], zr4, 0, 0, 0);
                acc = __builtin_amdgcn_mfma_f32_16x16x32_bf16(A1.v, w2f1[cb], acc, 0, 0, 0);
                pv0 += silu_f(acc[0] + bw[cb].x) * bw[cb].y;
                pv1 += silu_f(acc[1] + bw[cb].x) * bw[cb].y;
                pv2 += silu_f(acc[2] + bw[cb].x) * bw[cb].y;
                pv3 += silu_f(acc[3] + bw[cb].x) * bw[cb].y;
            }
            float pvv[4] = {pv0, pv1, pv2, pv3};
            #pragma unroll
            for (int r = 0; r < 4; ++r) {
                float v = pvv[r];
                v += __shfl_xor(v, 1);
                v += __shfl_xor(v, 2);
                v += __shfl_xor(v, 4);
                v += __shfl_xor(v, 8);
                if (lo == 0) {
                    int row = t * 16 + g * 4 + r;
                    Part[n][row] = Att[row * 9 + n] * v;
                }
            }
        }
    }

    __syncthreads();

    // final cross-basis reduce + store
    if (tid < ROWS_BLK) {
        float v = Att[tid * 9 + 8];   // tail'
        #pragma unroll
        for (int w = 0; w < 8; ++w) v += Part[w][tid];
        v = fminf(fmaxf(v, -1e6f), 1e6f);
        int rg = rowbase + tid;
        int bb, colo;
        if (fam == 0) { bb = rg / 120; colo = COL_PW + (rg - bb * 120); }
        else if (fam == 1) { bb = rg >> 4; colo = COL_ND + (rg & 15); }
        else { bb = rg; colo = COL_GL; }
        out[(size_t)bb * XCOLS + colo] = v;
    }
}

extern "C" void kernel_launch(void* const* d_in, const int* in_sizes, int n_in,
                              void* d_out, int out_size, void* d_ws, size_t ws_size,
                              hipStream_t stream) {
    const float* z = (const float*)d_in[0];
    const float* pw[12]; const float* nd[12]; const float* gl[12];
    for (int i = 0; i < 12; ++i) pw[i] = (const float*)d_in[1 + i];
    for (int i = 0; i < 12; ++i) nd[i] = (const float*)d_in[13 + i];
    for (int i = 0; i < 12; ++i) gl[i] = (const float*)d_in[25 + i];
    const float* sel_W1 = (const float*)d_in[37];
    const float* sel_b1 = (const float*)d_in[38];
    const float* sel_W2 = (const float*)d_in[39];
    const float* sel_b2 = (const float*)d_in[40];
    const float* sel_W3 = (const float*)d_in[41];
    const float* sel_b3 = (const float*)d_in[42];

    float* out = (float*)d_out;
    char* ws = (char*)d_ws;

    selgeom_kernel<<<BATCH, 64, 0, stream>>>(
        z, sel_W1, sel_b1, sel_W2, sel_b2, sel_W3, sel_b3,
        (float*)(ws + WS_SGATE), out);

    // param index order: W1,b1,W2,b2,W3,b3,scale,aW1,ab1,aW2,ab2,res
    AArgs apw = {pw[7], pw[8], pw[9], pw[10], pw[5], pw[6], pw[11]};
    AArgs anda = {nd[7], nd[8], nd[9], nd[10], nd[5], nd[6], nd[11]};
    AArgs agl = {gl[7], gl[8], gl[9], gl[10], gl[5], gl[6], gl[11]};
    PArgs ppw = {pw[0], pw[1], pw[2], pw[3], pw[4]};
    PArgs pnd = {nd[0], nd[1], nd[2], nd[3], nd[4]};
    PArgs pgl = {gl[0], gl[1], gl[2], gl[3], gl[4]};

    xprep_kernel<<<1096 + 128, 256, 0, stream>>>(z, apw, anda, agl, ppw, pnd, pgl, ws);

    basis_main_kernel<<<GL_BLK + PW_BLK + ND_BLK, 512, 0, stream>>>(ws, out);
}